// Round 4
// baseline (367.900 us; speedup 1.0000x reference)
//
#include <hip/hip_runtime.h>

// Problem constants
#define NPG   39
#define NGRAPH 8192
#define EPG   312           // input edges per graph
#define EDG   351           // + 39 self loops
#define E0    2555904       // total input edges (8192*312)
#define FDIM  4560
#define KP    4608          // padded K for bf16 GEMM (multiple of 128)

typedef __bf16 bf16x8 __attribute__((ext_vector_type(8)));
typedef float  f32x4  __attribute__((ext_vector_type(4)));
typedef float  f32x2  __attribute__((ext_vector_type(2)));

__device__ __forceinline__ unsigned short f2b(float f) {
  unsigned int u = __float_as_uint(f);
  u += 0x7fffu + ((u >> 16) & 1u);            // RNE to bf16
  return (unsigned short)(u >> 16);
}
__device__ __forceinline__ unsigned int pk2(float lo, float hi) {
  return (unsigned int)f2b(lo) | ((unsigned int)f2b(hi) << 16);
}
__device__ __forceinline__ float b2f_lo(unsigned int u) { return __uint_as_float(u << 16); }
__device__ __forceinline__ float b2f_hi(unsigned int u) { return __uint_as_float(u & 0xffff0000u); }
// wave-level "barrier": single wave per workgroup -> LDS drain + compiler fence
__device__ __forceinline__ void wsync() {
  asm volatile("s_waitcnt lgkmcnt(0)" ::: "memory");
}

// =================== per-graph LDS (one wave per graph) ===================
// Feature rows are bf16, strides multiples of 8 elems (16B) for b128 access;
// stride/8 odd => oct-index rotates across the 8 bank-quads row-to-row.
__shared__ alignas(16) unsigned short Abuf16[NPG * 72];  // 5616 B  layer inputs
__shared__ alignas(16) unsigned short Bbuf16[NPG * 72];  // 5616 B  matmul h1
__shared__ alignas(16) uint2 rec[EDG];                   // 2808 B  {alpha, src byte off}
__shared__ alignas(16) float bl[64];                     // padded bias
__shared__ float sn[40];                                 // src attention scalars
__shared__ unsigned char csr_src[EDG + 1];
__shared__ unsigned short csr_ptr[NPG + 1];

// ======================= fused GAT layer (per wave) =======================
// Fi/Fo feature dims; SIN/SOUT/SB row strides (elems); LPD lanes per dst in P4
template<int Fi, int Fo, int SIN, int SOUT, int SB, int LPD, bool WRA>
__device__ __forceinline__ void layer(float x0,
                                      const float* __restrict__ W,   // [Fi][Fo] row-major
                                      const float* __restrict__ as_,
                                      const float* __restrict__ ad_,
                                      const float* __restrict__ bias,
                                      unsigned short* __restrict__ f_row,
                                      int res_off, int out_off, int lane) {
  constexpr int OCT = (Fo + 7) / 8;                // feature octs (16B)
  constexpr int FoP = OCT * 8;
  constexpr int OPL = OCT / LPD;                   // octs per lane in P4
  constexpr int ITEMS = NPG * LPD;
  constexpr int SBB = SB * 2;                      // row stride bytes
  constexpr int LSH = (LPD == 1) ? 0 : ((LPD == 2) ? 1 : 2);

  bl[lane] = (lane < Fo) ? bias[lane] : 0.f;       // padded bias stage

  // ---------- P1/P2: h1 = h0 @ W, attention scalars, h1 -> B (bf16) ----------
  float d_reg = 0.f;
  if (lane < NPG) {
    float h1r[FoP];
#pragma unroll
    for (int o = 0; o < FoP; ++o) h1r[o] = 0.f;
    if constexpr (Fi == 1) {
#pragma unroll
      for (int o = 0; o < Fo; ++o) h1r[o] = x0 * W[o];
    } else {
#pragma unroll
      for (int iq = 0; iq < Fi / 8; ++iq) {
        uint4 u = *(const uint4*)&Abuf16[lane * SIN + 8 * iq];
        float xv[8];
        xv[0] = b2f_lo(u.x); xv[1] = b2f_hi(u.x);
        xv[2] = b2f_lo(u.y); xv[3] = b2f_hi(u.y);
        xv[4] = b2f_lo(u.z); xv[5] = b2f_hi(u.z);
        xv[6] = b2f_lo(u.w); xv[7] = b2f_hi(u.w);
#pragma unroll
        for (int ii = 0; ii < 8; ++ii) {
          int i = 8 * iq + ii;
          float v = xv[ii];
#pragma unroll
          for (int op = 0; op < FoP / 2; ++op) {   // packed pairs -> v_pk_fma
            f32x2 wv;
            wv.x = (2 * op     < Fo) ? W[i * Fo + 2 * op]     : 0.f;
            wv.y = (2 * op + 1 < Fo) ? W[i * Fo + 2 * op + 1] : 0.f;
            f32x2 hv = *(f32x2*)&h1r[2 * op];
            hv += wv * v;
            *(f32x2*)&h1r[2 * op] = hv;
          }
        }
      }
    }
    float s_reg = 0.f;
#pragma unroll
    for (int o = 0; o < Fo; ++o) { s_reg += h1r[o] * as_[o]; d_reg += h1r[o] * ad_[o]; }
    sn[lane] = s_reg;                              // LDS: safe under divergence
#pragma unroll
    for (int o = 0; o < OCT; ++o) {                // h1 -> B, one b128 per oct
      uint4 p;
      p.x = pk2(h1r[8 * o + 0], h1r[8 * o + 1]);
      p.y = pk2(h1r[8 * o + 2], h1r[8 * o + 3]);
      p.z = pk2(h1r[8 * o + 4], h1r[8 * o + 5]);
      p.w = pk2(h1r[8 * o + 6], h1r[8 * o + 7]);
      *(uint4*)&Bbuf16[lane * SB + 8 * o] = p;
    }
  }
  wsync();

  // ---------- P3: per-dst softmax -> normalized records {alpha, soff} ----------
  if (lane < NPG) {
    int rs = csr_ptr[lane], re = csr_ptr[lane + 1];
    float m = -3.4e38f;
    for (int k = rs; k < re; ++k) {
      int s = csr_src[k];
      float e = sn[s] + d_reg;
      e = (e >= 0.f) ? e : 0.2f * e;               // leaky_relu 0.2
      rec[k] = make_uint2(__float_as_uint(e), (unsigned int)(s * SBB));
      m = fmaxf(m, e);
    }
    float den = 0.f;
    for (int k = rs; k < re; ++k) {
      float w = __expf(__uint_as_float(rec[k].x) - m);
      den += w;
      rec[k].x = __float_as_uint(w);
    }
    float inv = 1.f / (den + 1e-16f);
    for (int k = rs; k < re; ++k)
      rec[k].x = __float_as_uint(__uint_as_float(rec[k].x) * inv);
  }
  wsync();

  // ---------- P4: aggregate + bias + relu + stores + pool acc ----------
  float pacc[OPL * 8];
#pragma unroll
  for (int i = 0; i < OPL * 8; ++i) pacc[i] = 0.f;
  for (int item = lane; item < ITEMS; item += 64) {
    int d = item >> LSH;
    int h = item & (LPD - 1);
    int rs = csr_ptr[d], re = csr_ptr[d + 1];
    float acc[OPL * 8];
#pragma unroll
    for (int i = 0; i < OPL * 8; ++i) acc[i] = 0.f;
    uint2 rc = rec[rs];                            // deg >= 1 (self loop)
    for (int k = rs; k < re; ++k) {
      int kn = (k + 1 < re) ? (k + 1) : k;
      uint2 rn = rec[kn];                          // prefetch next record
      float a = __uint_as_float(rc.x);
      const unsigned short* frow = &Bbuf16[(rc.y >> 1) + h * (OPL * 8)];
#pragma unroll
      for (int o = 0; o < OPL; ++o) {
        uint4 u = *(const uint4*)&frow[8 * o];
        acc[8 * o + 0] += b2f_lo(u.x) * a; acc[8 * o + 1] += b2f_hi(u.x) * a;
        acc[8 * o + 2] += b2f_lo(u.y) * a; acc[8 * o + 3] += b2f_hi(u.y) * a;
        acc[8 * o + 4] += b2f_lo(u.z) * a; acc[8 * o + 5] += b2f_hi(u.z) * a;
        acc[8 * o + 6] += b2f_lo(u.w) * a; acc[8 * o + 7] += b2f_hi(u.w) * a;
      }
      rc = rn;
    }
    int fb0 = h * (OPL * 8);
#pragma unroll
    for (int o = 0; o < OPL; ++o) {
      int fb = fb0 + 8 * o;
      f32x4 b0 = *(const f32x4*)&bl[fb];
      f32x4 b1 = *(const f32x4*)&bl[fb + 4];
      float v[8];
      v[0] = fmaxf(acc[8 * o + 0] + b0.x, 0.f); v[1] = fmaxf(acc[8 * o + 1] + b0.y, 0.f);
      v[2] = fmaxf(acc[8 * o + 2] + b0.z, 0.f); v[3] = fmaxf(acc[8 * o + 3] + b0.w, 0.f);
      v[4] = fmaxf(acc[8 * o + 4] + b1.x, 0.f); v[5] = fmaxf(acc[8 * o + 5] + b1.y, 0.f);
      v[6] = fmaxf(acc[8 * o + 6] + b1.z, 0.f); v[7] = fmaxf(acc[8 * o + 7] + b1.w, 0.f);
#pragma unroll
      for (int j = 0; j < 8; ++j) pacc[8 * o + j] = fmaxf(pacc[8 * o + j], v[j]);
      uint4 p;
      p.x = pk2(v[0], v[1]); p.y = pk2(v[2], v[3]);
      p.z = pk2(v[4], v[5]); p.w = pk2(v[6], v[7]);
      if constexpr (Fo == 9) {                     // stride-9 rows: scalar stores
        const unsigned short* pe = (const unsigned short*)&p;
#pragma unroll
        for (int j = 0; j < 8; ++j)
          if (fb + j < 9) f_row[res_off + d * 9 + fb + j] = pe[j];
      } else {
        *(uint4*)&f_row[res_off + d * Fo + fb] = p;
      }
      if constexpr (WRA) *(uint4*)&Abuf16[d * SOUT + fb] = p;
    }
  }

  // ---------- P5: per-graph max pool via register shuffle ----------
  // lane's h-class is fixed across its P4 items (64 % LPD == 0); reduce is in
  // uniform control flow (all 64 lanes), so shfl_xor is divergence-safe.
#pragma unroll
  for (int st = LPD; st < 64; st <<= 1) {
#pragma unroll
    for (int i = 0; i < OPL * 8; ++i) {
      float t = __shfl_xor(pacc[i], st);
      pacc[i] = fmaxf(pacc[i], t);
    }
  }
  if (lane < LPD) {
    if constexpr (Fo == 9) {                       // 9 elems: b128 + 1 scalar
      uint4 p;
      p.x = pk2(pacc[0], pacc[1]); p.y = pk2(pacc[2], pacc[3]);
      p.z = pk2(pacc[4], pacc[5]); p.w = pk2(pacc[6], pacc[7]);
      *(uint4*)&f_row[out_off] = p;
      f_row[out_off + 8] = f2b(pacc[8]);
    } else {
#pragma unroll
      for (int o = 0; o < OPL; ++o) {
        uint4 p;
        p.x = pk2(pacc[8 * o + 0], pacc[8 * o + 1]);
        p.y = pk2(pacc[8 * o + 2], pacc[8 * o + 3]);
        p.z = pk2(pacc[8 * o + 4], pacc[8 * o + 5]);
        p.w = pk2(pacc[8 * o + 6], pacc[8 * o + 7]);
        *(uint4*)&f_row[out_off + lane * (OPL * 8) + 8 * o] = p;
      }
    }
  }
  wsync();
}

// =========================== fused GAT kernel ===========================
__global__ __launch_bounds__(64, 3) void gat_fused(
    const float* __restrict__ x, const int* __restrict__ ei,
    const float* __restrict__ W1, const float* __restrict__ as1, const float* __restrict__ ad1, const float* __restrict__ b1,
    const float* __restrict__ W2, const float* __restrict__ as2, const float* __restrict__ ad2, const float* __restrict__ b2,
    const float* __restrict__ W3, const float* __restrict__ as3, const float* __restrict__ ad3, const float* __restrict__ b3,
    const float* __restrict__ W4, const float* __restrict__ as4, const float* __restrict__ ad4, const float* __restrict__ b4,
    unsigned short* __restrict__ f) {
  const int b = blockIdx.x;
  const int lane = threadIdx.x;                    // one wave per graph
  const int base = b * NPG;
  const int* srcg = ei + (size_t)b * EPG;
  const int* dstg = ei + E0 + (size_t)b * EPG;
  unsigned short* f_row = f + (size_t)b * KP;
  int* cnt = (int*)rec;                            // alias: rec unused until P3

  // x load, res0, out0, zero columns (k=39 inserted zero col; 4561.. pad)
  float xv = 0.f;
  if (lane < NPG) {
    xv = x[(size_t)base + lane];
    f_row[lane] = f2b(xv);
  }
  if (lane == 0) f_row[39] = 0;
  if (lane < KP - 4561) f_row[4561 + lane] = 0;
  float mx = (lane < NPG) ? xv : -3.4e38f;
#pragma unroll
  for (int st = 1; st < 64; st <<= 1) { float t = __shfl_xor(mx, st); mx = fmaxf(mx, t); }
  if (lane == 0) f_row[4447] = f2b(mx);            // out0 = max over raw x
  if (lane < NPG) cnt[lane] = 1;                   // self loop pre-count
  wsync();

  // degree count (edges stashed in registers for the scatter pass)
  int es[5], ed[5];
#pragma unroll
  for (int it = 0; it < 5; ++it) {
    int e = lane + 64 * it;
    if (e < EPG) {
      int s = srcg[e] - base, d = dstg[e] - base;
      s = min(max(s, 0), NPG - 1);
      d = min(max(d, 0), NPG - 1);
      es[it] = s; ed[it] = d;
      atomicAdd(&cnt[d], 1);
    } else { es[it] = -1; ed[it] = 0; }
  }
  wsync();

  // exclusive prefix sum via wave scan (uniform control flow)
  int c = (lane < NPG) ? cnt[lane] : 0;
  int v = c;
#pragma unroll
  for (int off = 1; off < 64; off <<= 1) { int t = __shfl_up(v, off); if (lane >= off) v += t; }
  int excl = v - c;
  if (lane < NPG) csr_ptr[lane] = (unsigned short)excl;
  if (lane == NPG - 1) csr_ptr[NPG] = (unsigned short)EDG;   // total is always 351
  wsync();
  if (lane < NPG) cnt[lane] = excl;                // running positions
  wsync();

  // scatter: self loops + edges
  if (lane < NPG) { int p = atomicAdd(&cnt[lane], 1); csr_src[p] = (unsigned char)lane; }
#pragma unroll
  for (int it = 0; it < 5; ++it) {
    if (es[it] >= 0) {
      int p = atomicAdd(&cnt[ed[it]], 1);
      p = min(p, EDG - 1);
      csr_src[p] = (unsigned char)es[it];
    }
  }
  wsync();

  //     Fi  Fo  SIN SOUT SB  LPD WRA            res   out
  layer< 1,  8,   8,  8,   8,  1, true >(xv, W1, as1, ad1, b1, f_row, 40,   4448, lane);
  layer< 8, 64,   8, 72,  72,  4, true >(0,  W2, as2, ad2, b2, f_row, 352,  4456, lane);
  layer<64, 32,  72, 40,  40,  2, true >(0,  W3, as3, ad3, b3, f_row, 2848, 4520, lane);
  layer<32,  9,  40,  0,  24,  1, false>(0,  W4, as4, ad4, b4, f_row, 4096, 4552, lane);
}

// ================= weight transpose + bf16 cast (per launch) =================
// PERM: apply the f-column permutation (insert zero col at k=39, shift +1)
template<bool PERM>
__global__ __launch_bounds__(256) void tcast(const float* __restrict__ in,
                                             unsigned short* __restrict__ out,
                                             int K, int NN, int Kpad) {
  __shared__ float tile[64 * 65];
  const int k0 = blockIdx.x * 64, n0 = blockIdx.y * 64;
  const int tid = threadIdx.x;
#pragma unroll
  for (int i = 0; i < 16; ++i) {
    int idx = i * 256 + tid;
    int r = idx >> 6, c = idx & 63;
    int k = k0 + r;
    int ko;
    if constexpr (PERM) {
      ko = (k < 39) ? k : ((k == 39 || k > FDIM) ? -1 : k - 1);
    } else {
      ko = (k < K) ? k : -1;
    }
    tile[r * 65 + c] = (ko >= 0) ? in[(size_t)ko * NN + n0 + c] : 0.f;
  }
  __syncthreads();
#pragma unroll
  for (int i = 0; i < 16; ++i) {
    int idx = i * 256 + tid;
    int r = idx >> 6, c = idx & 63;    // r: n-offset, c: k-offset
    out[(size_t)(n0 + r) * Kpad + k0 + c] = f2b(tile[c * 65 + r]);
  }
}

// =========================== bf16 MFMA GEMM ===========================
template<bool OUT_BF16>
__global__ __launch_bounds__(256) void mfma_gemm(const unsigned short* __restrict__ A,
    const unsigned short* __restrict__ Bt, unsigned short* __restrict__ Cb,
    float* __restrict__ Cf, const float* __restrict__ bias, int K, int N) {
  __shared__ alignas(16) unsigned short As[128 * 32];
  __shared__ alignas(16) unsigned short Bs[128 * 32];
  const int tid = threadIdx.x;
  const int lane = tid & 63;
  const int wave = tid >> 6;
  const int wy = wave >> 1, wx = wave & 1;
  const int m0 = blockIdx.y * 128, n0 = blockIdx.x * 128;

  f32x4 acc[4][4];
  const f32x4 z = {0.f, 0.f, 0.f, 0.f};
#pragma unroll
  for (int i = 0; i < 4; ++i)
#pragma unroll
    for (int j = 0; j < 4; ++j) acc[i][j] = z;

  const int lr = lane >> 2;
  const int lc = (lane & 3) * 8;
  const int q8 = (lane >> 4) * 8;
  const int rm = lane & 15;

  for (int k0 = 0; k0 < K; k0 += 32) {
    __syncthreads();
#pragma unroll
    for (int t = 0; t < 2; ++t) {
      int r0 = wave * 32 + t * 16;
      const unsigned short* ga = A  + (size_t)(m0 + r0 + lr) * K + k0 + lc;
      const unsigned short* gb = Bt + (size_t)(n0 + r0 + lr) * K + k0 + lc;
      __builtin_amdgcn_global_load_lds(
          (const __attribute__((address_space(1))) unsigned int*)(const void*)ga,
          (__attribute__((address_space(3))) unsigned int*)(void*)&As[r0 * 32], 16, 0, 0);
      __builtin_amdgcn_global_load_lds(
          (const __attribute__((address_space(1))) unsigned int*)(const void*)gb,
          (__attribute__((address_space(3))) unsigned int*)(void*)&Bs[r0 * 32], 16, 0, 0);
    }
    __syncthreads();
    bf16x8 af[4], bfr[4];
#pragma unroll
    for (int i = 0; i < 4; ++i) {
      af[i]  = *(const bf16x8*)&As[(wy * 64 + i * 16 + rm) * 32 + q8];
      bfr[i] = *(const bf16x8*)&Bs[(wx * 64 + i * 16 + rm) * 32 + q8];
    }
#pragma unroll
    for (int i = 0; i < 4; ++i)
#pragma unroll
      for (int j = 0; j < 4; ++j)
        acc[i][j] = __builtin_amdgcn_mfma_f32_16x16x32_bf16(af[i], bfr[j], acc[i][j], 0, 0, 0);
  }
  const int q4 = (lane >> 4) * 4;
#pragma unroll
  for (int i = 0; i < 4; ++i) {
#pragma unroll
    for (int j = 0; j < 4; ++j) {
      int row = m0 + wy * 64 + i * 16 + q4;
      int col = n0 + wx * 64 + j * 16 + rm;
      float bv = bias[col];
#pragma unroll
      for (int v = 0; v < 4; ++v) {
        float val = fmaxf(acc[i][j][v] + bv, 0.f);
        if constexpr (OUT_BF16) Cb[(size_t)(row + v) * N + col] = f2b(val);
        else                    Cf[(size_t)(row + v) * N + col] = val;
      }
    }
  }
}

// =========================== final 128->9 layer ===========================
__global__ __launch_bounds__(256) void mlp3(const float* __restrict__ g2,
                                            const float* __restrict__ w3,
                                            const float* __restrict__ b3,
                                            float* __restrict__ out) {
  __shared__ float gs[64 * 130];
  __shared__ float ws3[128 * 9];
  const int r0 = blockIdx.x * 64;
  const int tid = threadIdx.x;
  for (int i = tid; i < 64 * 128; i += 256)
    gs[(i >> 7) * 130 + (i & 127)] = g2[(size_t)r0 * 128 + i];
  for (int i = tid; i < 128 * 9; i += 256) ws3[i] = w3[i];
  __syncthreads();
  for (int idx = tid; idx < 64 * 9; idx += 256) {
    int r = idx / 9, c = idx - r * 9;
    float acc = b3[c];
#pragma unroll 8
    for (int k = 0; k < 128; ++k) acc += gs[r * 130 + k] * ws3[k * 9 + c];
    out[(size_t)(r0 + r) * 9 + c] = acc;
  }
}

// =========================== launch ===========================
extern "C" void kernel_launch(void* const* d_in, const int* in_sizes, int n_in,
                              void* d_out, int out_size, void* d_ws, size_t ws_size,
                              hipStream_t stream) {
  const float* x   = (const float*)d_in[0];
  const int*   ei  = (const int*)d_in[1];
  const float* W1  = (const float*)d_in[3];
  const float* as1 = (const float*)d_in[4];
  const float* ad1 = (const float*)d_in[5];
  const float* b1  = (const float*)d_in[6];
  const float* W2  = (const float*)d_in[7];
  const float* as2 = (const float*)d_in[8];
  const float* ad2 = (const float*)d_in[9];
  const float* b2  = (const float*)d_in[10];
  const float* W3  = (const float*)d_in[11];
  const float* as3 = (const float*)d_in[12];
  const float* ad3 = (const float*)d_in[13];
  const float* b3  = (const float*)d_in[14];
  const float* W4  = (const float*)d_in[15];
  const float* as4 = (const float*)d_in[16];
  const float* ad4 = (const float*)d_in[17];
  const float* b4  = (const float*)d_in[18];
  const float* lw1 = (const float*)d_in[19];
  const float* lb1 = (const float*)d_in[20];
  const float* lw2 = (const float*)d_in[21];
  const float* lb2 = (const float*)d_in[22];
  const float* lw3 = (const float*)d_in[23];
  const float* lb3 = (const float*)d_in[24];
  float* out = (float*)d_out;

  // workspace carve-up (bf16 stored as u16)
  unsigned short* f   = (unsigned short*)d_ws;            // [8192][4608] bf16
  unsigned short* w1t = f   + (size_t)NGRAPH * KP;        // [1024][4608] bf16
  unsigned short* w2t = w1t + (size_t)1024 * KP;          // [128][1024]  bf16
  unsigned short* g1  = w2t + (size_t)128 * 1024;         // [8192][1024] bf16
  float*          g2  = (float*)(g1 + (size_t)NGRAPH * 1024); // [8192][128] f32

  tcast<true ><<<dim3(KP / 64, 1024 / 64), 256, 0, stream>>>(lw1, w1t, FDIM, 1024, KP);
  tcast<false><<<dim3(1024 / 64, 128 / 64), 256, 0, stream>>>(lw2, w2t, 1024, 128, 1024);

  gat_fused<<<NGRAPH, 64, 0, stream>>>(x, ei,
      W1, as1, ad1, b1, W2, as2, ad2, b2, W3, as3, ad3, b3, W4, as4, ad4, b4, f);

  mfma_gemm<true ><<<dim3(1024 / 128, NGRAPH / 128), 256, 0, stream>>>(
      f, w1t, g1, nullptr, lb1, KP, 1024);
  mfma_gemm<false><<<dim3(128 / 128, NGRAPH / 128), 256, 0, stream>>>(
      g1, w2t, nullptr, g2, lb2, 1024, 128);

  mlp3<<<NGRAPH / 64, 256, 0, stream>>>(g2, lw3, lb3, out);
}

// Round 5
// 316.263 us; speedup vs baseline: 1.1633x; 1.1633x over previous
//
#include <hip/hip_runtime.h>

// Problem constants
#define NPG   39
#define NGRAPH 8192
#define EPG   312           // input edges per graph
#define EDG   351           // + 39 self loops
#define E0    2555904       // total input edges (8192*312)
#define FDIM  4560
#define KP    4608          // padded K for bf16 GEMM (multiple of 128)

typedef __bf16 bf16x8 __attribute__((ext_vector_type(8)));
typedef float  f32x4  __attribute__((ext_vector_type(4)));
typedef float  f32x2  __attribute__((ext_vector_type(2)));

__device__ __forceinline__ unsigned short f2b(float f) {
  unsigned int u = __float_as_uint(f);
  u += 0x7fffu + ((u >> 16) & 1u);            // RNE to bf16
  return (unsigned short)(u >> 16);
}
__device__ __forceinline__ unsigned int pk2(float lo, float hi) {
  return (unsigned int)f2b(lo) | ((unsigned int)f2b(hi) << 16);
}
__device__ __forceinline__ float b2f_lo(unsigned int u) { return __uint_as_float(u << 16); }
__device__ __forceinline__ float b2f_hi(unsigned int u) { return __uint_as_float(u & 0xffff0000u); }
// wave-level "barrier": single wave per workgroup -> LDS drain + compiler fence
__device__ __forceinline__ void wsync() {
  asm volatile("s_waitcnt lgkmcnt(0)" ::: "memory");
}
// store->load fence for same-wave global RAW (f_row reuse across layers)
__device__ __forceinline__ void gsync() {
  asm volatile("s_waitcnt vmcnt(0) lgkmcnt(0)" ::: "memory");
}

// =================== per-graph LDS (one wave per graph) ===================
// No A-buffer: layer inputs are read back from the graph's f-row in global
// (L2-resident, written by the previous layer's P4). Total ~9.3 KB =>
// 16 single-wave workgroups/CU (the HW cap), 4 waves/SIMD.
__shared__ alignas(16) unsigned short Bbuf16[NPG * 72];  // 5616 B  matmul h1
__shared__ alignas(16) uint2 rec[EDG];                   // 2808 B  {alpha, src byte off}
__shared__ alignas(16) float bl[64];                     // padded bias
__shared__ float sn[40];                                 // src attention scalars
__shared__ unsigned char csr_src[EDG + 1];
__shared__ unsigned short csr_ptr[NPG + 1];

// ======================= fused GAT layer (per wave) =======================
// Fi/Fo feature dims; SB: Bbuf row stride (elems); LPD: lanes per dst in P4.
// Input row: f_row[in_off + node*Fi] (bf16, contiguous); Fi==1 uses x0 reg.
template<int Fi, int Fo, int SB, int LPD>
__device__ __forceinline__ void layer(float x0, int in_off,
                                      const float* __restrict__ W,   // [Fi][Fo] row-major
                                      const float* __restrict__ as_,
                                      const float* __restrict__ ad_,
                                      const float* __restrict__ bias,
                                      unsigned short* __restrict__ f_row,
                                      int res_off, int out_off, int lane) {
  constexpr int OCT = (Fo + 7) / 8;                // feature octs (16B)
  constexpr int FoP = OCT * 8;
  constexpr int OPL = OCT / LPD;                   // octs per lane in P4
  constexpr int ITEMS = NPG * LPD;
  constexpr int SBB = SB * 2;                      // row stride bytes
  constexpr int LSH = (LPD == 1) ? 0 : ((LPD == 2) ? 1 : 2);

  bl[lane] = (lane < Fo) ? bias[lane] : 0.f;       // padded bias stage

  // ---------- P1/P2: h1 = h0 @ W, attention scalars, h1 -> B (bf16) ----------
  if constexpr (Fi > 1) gsync();                   // prior P4 f-stores must land
  float d_reg = 0.f;
  if (lane < NPG) {
    float h1r[FoP];
#pragma unroll
    for (int o = 0; o < FoP; ++o) h1r[o] = 0.f;
    if constexpr (Fi == 1) {
#pragma unroll
      for (int o = 0; o < Fo; ++o) h1r[o] = x0 * W[o];
    } else {
      const unsigned short* in_row = f_row + in_off + lane * Fi;
#pragma unroll
      for (int iq = 0; iq < Fi / 8; ++iq) {
        uint4 u = *(const uint4*)&in_row[8 * iq];  // global b128, L2-hit
        float xv[8];
        xv[0] = b2f_lo(u.x); xv[1] = b2f_hi(u.x);
        xv[2] = b2f_lo(u.y); xv[3] = b2f_hi(u.y);
        xv[4] = b2f_lo(u.z); xv[5] = b2f_hi(u.z);
        xv[6] = b2f_lo(u.w); xv[7] = b2f_hi(u.w);
#pragma unroll
        for (int ii = 0; ii < 8; ++ii) {
          int i = 8 * iq + ii;
          float v = xv[ii];
#pragma unroll
          for (int op = 0; op < FoP / 2; ++op) {   // packed pairs -> v_pk_fma
            f32x2 wv;
            wv.x = (2 * op     < Fo) ? W[i * Fo + 2 * op]     : 0.f;
            wv.y = (2 * op + 1 < Fo) ? W[i * Fo + 2 * op + 1] : 0.f;
            f32x2 hv = *(f32x2*)&h1r[2 * op];
            hv += wv * v;
            *(f32x2*)&h1r[2 * op] = hv;
          }
        }
      }
    }
    float s_reg = 0.f;
#pragma unroll
    for (int o = 0; o < Fo; ++o) { s_reg += h1r[o] * as_[o]; d_reg += h1r[o] * ad_[o]; }
    sn[lane] = s_reg;                              // LDS: safe under divergence
#pragma unroll
    for (int o = 0; o < OCT; ++o) {                // h1 -> B, one b128 per oct
      uint4 p;
      p.x = pk2(h1r[8 * o + 0], h1r[8 * o + 1]);
      p.y = pk2(h1r[8 * o + 2], h1r[8 * o + 3]);
      p.z = pk2(h1r[8 * o + 4], h1r[8 * o + 5]);
      p.w = pk2(h1r[8 * o + 6], h1r[8 * o + 7]);
      *(uint4*)&Bbuf16[lane * SB + 8 * o] = p;
    }
  }
  wsync();

  // ---------- P3: per-dst softmax -> normalized records {alpha, soff} ----------
  if (lane < NPG) {
    int rs = csr_ptr[lane], re = csr_ptr[lane + 1];
    float m = -3.4e38f;
    for (int k = rs; k < re; ++k) {
      int s = csr_src[k];
      float e = sn[s] + d_reg;
      e = (e >= 0.f) ? e : 0.2f * e;               // leaky_relu 0.2
      rec[k] = make_uint2(__float_as_uint(e), (unsigned int)(s * SBB));
      m = fmaxf(m, e);
    }
    float den = 0.f;
    for (int k = rs; k < re; ++k) {
      float w = __expf(__uint_as_float(rec[k].x) - m);
      den += w;
      rec[k].x = __float_as_uint(w);
    }
    float inv = 1.f / (den + 1e-16f);
    for (int k = rs; k < re; ++k)
      rec[k].x = __float_as_uint(__uint_as_float(rec[k].x) * inv);
  }
  wsync();

  // ---------- P4: aggregate + bias + relu + f-row stores + pool acc ----------
  float pacc[OPL * 8];
#pragma unroll
  for (int i = 0; i < OPL * 8; ++i) pacc[i] = 0.f;
  for (int item = lane; item < ITEMS; item += 64) {
    int d = item >> LSH;
    int h = item & (LPD - 1);
    int rs = csr_ptr[d], re = csr_ptr[d + 1];
    float acc[OPL * 8];
#pragma unroll
    for (int i = 0; i < OPL * 8; ++i) acc[i] = 0.f;
    uint2 rc = rec[rs];                            // deg >= 1 (self loop)
    for (int k = rs; k < re; ++k) {
      int kn = (k + 1 < re) ? (k + 1) : k;
      uint2 rn = rec[kn];                          // prefetch next record
      float a = __uint_as_float(rc.x);
      const unsigned short* frow = &Bbuf16[(rc.y >> 1) + h * (OPL * 8)];
#pragma unroll
      for (int o = 0; o < OPL; ++o) {
        uint4 u = *(const uint4*)&frow[8 * o];
        acc[8 * o + 0] += b2f_lo(u.x) * a; acc[8 * o + 1] += b2f_hi(u.x) * a;
        acc[8 * o + 2] += b2f_lo(u.y) * a; acc[8 * o + 3] += b2f_hi(u.y) * a;
        acc[8 * o + 4] += b2f_lo(u.z) * a; acc[8 * o + 5] += b2f_hi(u.z) * a;
        acc[8 * o + 6] += b2f_lo(u.w) * a; acc[8 * o + 7] += b2f_hi(u.w) * a;
      }
      rc = rn;
    }
    int fb0 = h * (OPL * 8);
#pragma unroll
    for (int o = 0; o < OPL; ++o) {
      int fb = fb0 + 8 * o;
      f32x4 b0 = *(const f32x4*)&bl[fb];
      f32x4 b1 = *(const f32x4*)&bl[fb + 4];
      float v[8];
      v[0] = fmaxf(acc[8 * o + 0] + b0.x, 0.f); v[1] = fmaxf(acc[8 * o + 1] + b0.y, 0.f);
      v[2] = fmaxf(acc[8 * o + 2] + b0.z, 0.f); v[3] = fmaxf(acc[8 * o + 3] + b0.w, 0.f);
      v[4] = fmaxf(acc[8 * o + 4] + b1.x, 0.f); v[5] = fmaxf(acc[8 * o + 5] + b1.y, 0.f);
      v[6] = fmaxf(acc[8 * o + 6] + b1.z, 0.f); v[7] = fmaxf(acc[8 * o + 7] + b1.w, 0.f);
#pragma unroll
      for (int j = 0; j < 8; ++j) pacc[8 * o + j] = fmaxf(pacc[8 * o + j], v[j]);
      uint4 p;
      p.x = pk2(v[0], v[1]); p.y = pk2(v[2], v[3]);
      p.z = pk2(v[4], v[5]); p.w = pk2(v[6], v[7]);
      if constexpr (Fo == 9) {                     // stride-9 rows: scalar stores
        const unsigned short* pe = (const unsigned short*)&p;
#pragma unroll
        for (int j = 0; j < 8; ++j)
          if (fb + j < 9) f_row[res_off + d * 9 + fb + j] = pe[j];
      } else {
        *(uint4*)&f_row[res_off + d * Fo + fb] = p;
      }
    }
  }

  // ---------- P5: per-graph max pool via register shuffle ----------
  // lane's h-class is fixed across its P4 items (64 % LPD == 0); reduce is in
  // uniform control flow (all 64 lanes), so shfl_xor is divergence-safe.
#pragma unroll
  for (int st = LPD; st < 64; st <<= 1) {
#pragma unroll
    for (int i = 0; i < OPL * 8; ++i) {
      float t = __shfl_xor(pacc[i], st);
      pacc[i] = fmaxf(pacc[i], t);
    }
  }
  if (lane < LPD) {
    if constexpr (Fo == 9) {                       // 9 elems: b128 + 1 scalar
      uint4 p;
      p.x = pk2(pacc[0], pacc[1]); p.y = pk2(pacc[2], pacc[3]);
      p.z = pk2(pacc[4], pacc[5]); p.w = pk2(pacc[6], pacc[7]);
      *(uint4*)&f_row[out_off] = p;
      f_row[out_off + 8] = f2b(pacc[8]);
    } else {
#pragma unroll
      for (int o = 0; o < OPL; ++o) {
        uint4 p;
        p.x = pk2(pacc[8 * o + 0], pacc[8 * o + 1]);
        p.y = pk2(pacc[8 * o + 2], pacc[8 * o + 3]);
        p.z = pk2(pacc[8 * o + 4], pacc[8 * o + 5]);
        p.w = pk2(pacc[8 * o + 6], pacc[8 * o + 7]);
        *(uint4*)&f_row[out_off + lane * (OPL * 8) + 8 * o] = p;
      }
    }
  }
  wsync();
}

// =========================== fused GAT kernel ===========================
__global__ __launch_bounds__(64, 4) void gat_fused(
    const float* __restrict__ x, const int* __restrict__ ei,
    const float* __restrict__ W1, const float* __restrict__ as1, const float* __restrict__ ad1, const float* __restrict__ b1,
    const float* __restrict__ W2, const float* __restrict__ as2, const float* __restrict__ ad2, const float* __restrict__ b2,
    const float* __restrict__ W3, const float* __restrict__ as3, const float* __restrict__ ad3, const float* __restrict__ b3,
    const float* __restrict__ W4, const float* __restrict__ as4, const float* __restrict__ ad4, const float* __restrict__ b4,
    unsigned short* __restrict__ f) {
  const int b = blockIdx.x;
  const int lane = threadIdx.x;                    // one wave per graph
  const int base = b * NPG;
  const int* srcg = ei + (size_t)b * EPG;
  const int* dstg = ei + E0 + (size_t)b * EPG;
  unsigned short* f_row = f + (size_t)b * KP;
  int* cnt = (int*)rec;                            // alias: rec unused until P3

  // x load, res0, out0, zero columns (k=39 inserted zero col; 4561.. pad)
  float xv = 0.f;
  if (lane < NPG) {
    xv = x[(size_t)base + lane];
    f_row[lane] = f2b(xv);
  }
  if (lane == 0) f_row[39] = 0;
  if (lane < KP - 4561) f_row[4561 + lane] = 0;
  float mx = (lane < NPG) ? xv : -3.4e38f;
#pragma unroll
  for (int st = 1; st < 64; st <<= 1) { float t = __shfl_xor(mx, st); mx = fmaxf(mx, t); }
  if (lane == 0) f_row[4447] = f2b(mx);            // out0 = max over raw x
  if (lane < NPG) cnt[lane] = 1;                   // self loop pre-count
  wsync();

  // degree count (edges stashed in registers for the scatter pass)
  int es[5], ed[5];
#pragma unroll
  for (int it = 0; it < 5; ++it) {
    int e = lane + 64 * it;
    if (e < EPG) {
      int s = srcg[e] - base, d = dstg[e] - base;
      s = min(max(s, 0), NPG - 1);
      d = min(max(d, 0), NPG - 1);
      es[it] = s; ed[it] = d;
      atomicAdd(&cnt[d], 1);
    } else { es[it] = -1; ed[it] = 0; }
  }
  wsync();

  // exclusive prefix sum via wave scan (uniform control flow)
  int c = (lane < NPG) ? cnt[lane] : 0;
  int v = c;
#pragma unroll
  for (int off = 1; off < 64; off <<= 1) { int t = __shfl_up(v, off); if (lane >= off) v += t; }
  int excl = v - c;
  if (lane < NPG) csr_ptr[lane] = (unsigned short)excl;
  if (lane == NPG - 1) csr_ptr[NPG] = (unsigned short)EDG;   // total is always 351
  wsync();
  if (lane < NPG) cnt[lane] = excl;                // running positions
  wsync();

  // scatter: self loops + edges
  if (lane < NPG) { int p = atomicAdd(&cnt[lane], 1); csr_src[p] = (unsigned char)lane; }
#pragma unroll
  for (int it = 0; it < 5; ++it) {
    if (es[it] >= 0) {
      int p = atomicAdd(&cnt[ed[it]], 1);
      p = min(p, EDG - 1);
      csr_src[p] = (unsigned char)es[it];
    }
  }
  wsync();

  //     Fi  Fo  SB  LPD        in_off              res   out
  layer< 1,  8,   8,  1>(xv, 0,    W1, as1, ad1, b1, f_row, 40,   4448, lane);
  layer< 8, 64,  72,  4>(0,  40,   W2, as2, ad2, b2, f_row, 352,  4456, lane);
  layer<64, 32,  40,  2>(0,  352,  W3, as3, ad3, b3, f_row, 2848, 4520, lane);
  layer<32,  9,  24,  1>(0,  2848, W4, as4, ad4, b4, f_row, 4096, 4552, lane);
}

// ================= weight transpose + bf16 cast (per launch) =================
// PERM: apply the f-column permutation (insert zero col at k=39, shift +1)
template<bool PERM>
__global__ __launch_bounds__(256) void tcast(const float* __restrict__ in,
                                             unsigned short* __restrict__ out,
                                             int K, int NN, int Kpad) {
  __shared__ float tile[64 * 65];
  const int k0 = blockIdx.x * 64, n0 = blockIdx.y * 64;
  const int tid = threadIdx.x;
#pragma unroll
  for (int i = 0; i < 16; ++i) {
    int idx = i * 256 + tid;
    int r = idx >> 6, c = idx & 63;
    int k = k0 + r;
    int ko;
    if constexpr (PERM) {
      ko = (k < 39) ? k : ((k == 39 || k > FDIM) ? -1 : k - 1);
    } else {
      ko = (k < K) ? k : -1;
    }
    tile[r * 65 + c] = (ko >= 0) ? in[(size_t)ko * NN + n0 + c] : 0.f;
  }
  __syncthreads();
#pragma unroll
  for (int i = 0; i < 16; ++i) {
    int idx = i * 256 + tid;
    int r = idx >> 6, c = idx & 63;    // r: n-offset, c: k-offset
    out[(size_t)(n0 + r) * Kpad + k0 + c] = f2b(tile[c * 65 + r]);
  }
}

// =========================== bf16 MFMA GEMM ===========================
template<bool OUT_BF16>
__global__ __launch_bounds__(256) void mfma_gemm(const unsigned short* __restrict__ A,
    const unsigned short* __restrict__ Bt, unsigned short* __restrict__ Cb,
    float* __restrict__ Cf, const float* __restrict__ bias, int K, int N) {
  __shared__ alignas(16) unsigned short As[128 * 32];
  __shared__ alignas(16) unsigned short Bs[128 * 32];
  const int tid = threadIdx.x;
  const int lane = tid & 63;
  const int wave = tid >> 6;
  const int wy = wave >> 1, wx = wave & 1;
  const int m0 = blockIdx.y * 128, n0 = blockIdx.x * 128;

  f32x4 acc[4][4];
  const f32x4 z = {0.f, 0.f, 0.f, 0.f};
#pragma unroll
  for (int i = 0; i < 4; ++i)
#pragma unroll
    for (int j = 0; j < 4; ++j) acc[i][j] = z;

  const int lr = lane >> 2;
  const int lc = (lane & 3) * 8;
  const int q8 = (lane >> 4) * 8;
  const int rm = lane & 15;

  for (int k0 = 0; k0 < K; k0 += 32) {
    __syncthreads();
#pragma unroll
    for (int t = 0; t < 2; ++t) {
      int r0 = wave * 32 + t * 16;
      const unsigned short* ga = A  + (size_t)(m0 + r0 + lr) * K + k0 + lc;
      const unsigned short* gb = Bt + (size_t)(n0 + r0 + lr) * K + k0 + lc;
      __builtin_amdgcn_global_load_lds(
          (const __attribute__((address_space(1))) unsigned int*)(const void*)ga,
          (__attribute__((address_space(3))) unsigned int*)(void*)&As[r0 * 32], 16, 0, 0);
      __builtin_amdgcn_global_load_lds(
          (const __attribute__((address_space(1))) unsigned int*)(const void*)gb,
          (__attribute__((address_space(3))) unsigned int*)(void*)&Bs[r0 * 32], 16, 0, 0);
    }
    __syncthreads();
    bf16x8 af[4], bfr[4];
#pragma unroll
    for (int i = 0; i < 4; ++i) {
      af[i]  = *(const bf16x8*)&As[(wy * 64 + i * 16 + rm) * 32 + q8];
      bfr[i] = *(const bf16x8*)&Bs[(wx * 64 + i * 16 + rm) * 32 + q8];
    }
#pragma unroll
    for (int i = 0; i < 4; ++i)
#pragma unroll
      for (int j = 0; j < 4; ++j)
        acc[i][j] = __builtin_amdgcn_mfma_f32_16x16x32_bf16(af[i], bfr[j], acc[i][j], 0, 0, 0);
  }
  const int q4 = (lane >> 4) * 4;
#pragma unroll
  for (int i = 0; i < 4; ++i) {
#pragma unroll
    for (int j = 0; j < 4; ++j) {
      int row = m0 + wy * 64 + i * 16 + q4;
      int col = n0 + wx * 64 + j * 16 + rm;
      float bv = bias[col];
#pragma unroll
      for (int v = 0; v < 4; ++v) {
        float val = fmaxf(acc[i][j][v] + bv, 0.f);
        if constexpr (OUT_BF16) Cb[(size_t)(row + v) * N + col] = f2b(val);
        else                    Cf[(size_t)(row + v) * N + col] = val;
      }
    }
  }
}

// =========================== final 128->9 layer ===========================
__global__ __launch_bounds__(256) void mlp3(const float* __restrict__ g2,
                                            const float* __restrict__ w3,
                                            const float* __restrict__ b3,
                                            float* __restrict__ out) {
  __shared__ float gs[64 * 130];
  __shared__ float ws3[128 * 9];
  const int r0 = blockIdx.x * 64;
  const int tid = threadIdx.x;
  for (int i = tid; i < 64 * 128; i += 256)
    gs[(i >> 7) * 130 + (i & 127)] = g2[(size_t)r0 * 128 + i];
  for (int i = tid; i < 128 * 9; i += 256) ws3[i] = w3[i];
  __syncthreads();
  for (int idx = tid; idx < 64 * 9; idx += 256) {
    int r = idx / 9, c = idx - r * 9;
    float acc = b3[c];
#pragma unroll 8
    for (int k = 0; k < 128; ++k) acc += gs[r * 130 + k] * ws3[k * 9 + c];
    out[(size_t)(r0 + r) * 9 + c] = acc;
  }
}

// =========================== launch ===========================
extern "C" void kernel_launch(void* const* d_in, const int* in_sizes, int n_in,
                              void* d_out, int out_size, void* d_ws, size_t ws_size,
                              hipStream_t stream) {
  const float* x   = (const float*)d_in[0];
  const int*   ei  = (const int*)d_in[1];
  const float* W1  = (const float*)d_in[3];
  const float* as1 = (const float*)d_in[4];
  const float* ad1 = (const float*)d_in[5];
  const float* b1  = (const float*)d_in[6];
  const float* W2  = (const float*)d_in[7];
  const float* as2 = (const float*)d_in[8];
  const float* ad2 = (const float*)d_in[9];
  const float* b2  = (const float*)d_in[10];
  const float* W3  = (const float*)d_in[11];
  const float* as3 = (const float*)d_in[12];
  const float* ad3 = (const float*)d_in[13];
  const float* b3  = (const float*)d_in[14];
  const float* W4  = (const float*)d_in[15];
  const float* as4 = (const float*)d_in[16];
  const float* ad4 = (const float*)d_in[17];
  const float* b4  = (const float*)d_in[18];
  const float* lw1 = (const float*)d_in[19];
  const float* lb1 = (const float*)d_in[20];
  const float* lw2 = (const float*)d_in[21];
  const float* lb2 = (const float*)d_in[22];
  const float* lw3 = (const float*)d_in[23];
  const float* lb3 = (const float*)d_in[24];
  float* out = (float*)d_out;

  // workspace carve-up (bf16 stored as u16)
  unsigned short* f   = (unsigned short*)d_ws;            // [8192][4608] bf16
  unsigned short* w1t = f   + (size_t)NGRAPH * KP;        // [1024][4608] bf16
  unsigned short* w2t = w1t + (size_t)1024 * KP;          // [128][1024]  bf16
  unsigned short* g1  = w2t + (size_t)128 * 1024;         // [8192][1024] bf16
  float*          g2  = (float*)(g1 + (size_t)NGRAPH * 1024); // [8192][128] f32

  tcast<true ><<<dim3(KP / 64, 1024 / 64), 256, 0, stream>>>(lw1, w1t, FDIM, 1024, KP);
  tcast<false><<<dim3(1024 / 64, 128 / 64), 256, 0, stream>>>(lw2, w2t, 1024, 128, 1024);

  gat_fused<<<NGRAPH, 64, 0, stream>>>(x, ei,
      W1, as1, ad1, b1, W2, as2, ad2, b2, W3, as3, ad3, b3, W4, as4, ad4, b4, f);

  mfma_gemm<true ><<<dim3(1024 / 128, NGRAPH / 128), 256, 0, stream>>>(
      f, w1t, g1, nullptr, lb1, KP, 1024);
  mfma_gemm<false><<<dim3(128 / 128, NGRAPH / 128), 256, 0, stream>>>(
      g1, w2t, nullptr, g2, lb2, 1024, 128);

  mlp3<<<NGRAPH / 64, 256, 0, stream>>>(g2, lw3, lb3, out);
}

// Round 7
// 263.384 us; speedup vs baseline: 1.3968x; 1.2008x over previous
//
#include <hip/hip_runtime.h>

// Problem constants
#define NPG   39
#define NGRAPH 8192
#define EPG   312           // input edges per graph
#define EDG   351           // + 39 self loops
#define E0    2555904       // total input edges (8192*312)
#define FDIM  4560
#define KP    4608          // padded K for bf16 GEMM (multiple of 128)

typedef __bf16 bf16x8 __attribute__((ext_vector_type(8)));
typedef float  f32x4  __attribute__((ext_vector_type(4)));

__device__ __forceinline__ unsigned short f2b(float f) {
  unsigned int u = __float_as_uint(f);
  u += 0x7fffu + ((u >> 16) & 1u);            // RNE to bf16
  return (unsigned short)(u >> 16);
}
__device__ __forceinline__ unsigned int pk2(float lo, float hi) {
  return (unsigned int)f2b(lo) | ((unsigned int)f2b(hi) << 16);
}
__device__ __forceinline__ float b2f(unsigned short u) {
  return __uint_as_float((unsigned int)u << 16);
}
// wave-level "barrier": single wave per workgroup -> LDS drain + compiler fence
__device__ __forceinline__ void wsync() {
  asm volatile("s_waitcnt lgkmcnt(0)" ::: "memory");
}
// drain global stores (f_row RAW across layers, same CU)
__device__ __forceinline__ void gsync() {
  asm volatile("s_waitcnt vmcnt(0) lgkmcnt(0)" ::: "memory");
}

// =================== per-graph LDS (one wave per graph) ===================
// Htb:  H^T in B-fragment order: [feat 0..31][src-k 0..63] bf16, oct-XOR-swizzled
//       (elem (p,k) at p*64 + ((k>>3)^(p&7))*8 + (k&7)). Layer2 uses 2 halves.
// alf16: dense attention matrix A[dst 0..39][src-k 0..63] bf16, same swizzle.
//       Zeroed each layer => k in [39,64) contributes exactly 0 to MFMA.
//       DUPLICATE EDGES ACCUMULATE (RMW) — the reference counts each instance.
// Total ~10.0 KB -> 16 single-wave workgroups/CU (the cap).
__shared__ alignas(16) unsigned short Htb[32 * 64];    // 4096 B
__shared__ alignas(16) unsigned short alf16[40 * 64];  // 5120 B
__shared__ float sn[40];                               // src attn scalars (alias: cnt)
__shared__ float dn[48];                               // d-dot, then 1/den (pad 48)
__shared__ unsigned char csr_src[EDG + 1];
__shared__ unsigned short csr_ptr[NPG + 1];

// ======================= fused GAT layer (per wave) =======================
// Fi,Fo: dims. KPAD: Wb row stride. KT1: P1 k-tiles. NT_STORE: feature n-tiles.
// HALVES: Ht passes (l2 only). DT: dots n-tile index. SCOL/DCOL: lane (l&15)
// holding the s/d dot column (hi at SCOL, lo at SCOL^4; combined via shfl).
template<int Fi, int Fo, int KPAD, int KT1, int NT_STORE, int HALVES,
         int DT, int SCOL, int DCOL>
__device__ __forceinline__ void layerM(float x0,
                                       const unsigned short* __restrict__ Wb,
                                       const float* __restrict__ W1,
                                       const float* __restrict__ as1,
                                       const float* __restrict__ ad1,
                                       const float* __restrict__ bias,
                                       unsigned short* __restrict__ f_row,
                                       int in_off, int res_off, int out_off,
                                       int lane) {
  constexpr int NTH = NT_STORE / HALVES;
  const int r15 = lane & 15, g = lane >> 4;
  const f32x4 z = {0.f, 0.f, 0.f, 0.f};
  const uint4 z4 = {0u, 0u, 0u, 0u};

  // ---- zero alpha (stale entries from previous layer; also k-padding) ----
#pragma unroll
  for (int i = 0; i < 5; ++i) *(uint4*)&alf16[lane * 8 + i * 512] = z4;

  // ---- P1-dots: attention scalars via 2 extra GEMM columns ----
  if constexpr (Fi == 1) {
    // layer 1: scalar path. h[o] = x*W1[o]; s = x*(W1.as1); d = x*(W1.ad1)
    float was = 0.f, wad = 0.f;
#pragma unroll
    for (int o = 0; o < 8; ++o) { float w = W1[o]; was += w * as1[o]; wad += w * ad1[o]; }
    if (lane < NPG) {
      sn[lane] = x0 * was; dn[lane] = x0 * wad;
#pragma unroll
      for (int o = 0; o < 8; ++o) {
        int idx = o * 64 + ((((lane >> 3) ^ (o & 7)) << 3)) + (lane & 7);
        Htb[idx] = f2b(x0 * W1[o]);
      }
    }
  } else {
    gsync();                                   // prior layer's f stores
    f32x4 cd[3];
#pragma unroll
    for (int mt = 0; mt < 3; ++mt) cd[mt] = z;
#pragma unroll
    for (int kt = 0; kt < KT1; ++kt) {
      bf16x8 aF[3];
#pragma unroll
      for (int mt = 0; mt < 3; ++mt)
        aF[mt] = *(const bf16x8*)&f_row[in_off + (16 * mt + r15) * Fi + kt * 32 + g * 8];
      bf16x8 bD = *(const bf16x8*)&Wb[(16 * DT + r15) * KPAD + kt * 32 + g * 8];
#pragma unroll
      for (int mt = 0; mt < 3; ++mt)
        cd[mt] = __builtin_amdgcn_mfma_f32_16x16x32_bf16(aF[mt], bD, cd[mt], 0, 0, 0);
    }
#pragma unroll
    for (int mt = 0; mt < 3; ++mt)
#pragma unroll
      for (int v = 0; v < 4; ++v) {
        float t = cd[mt][v] + __shfl_xor(cd[mt][v], 4);   // hi + lo column
        int r = 16 * mt + g * 4 + v;
        if (r15 == SCOL && r < NPG) sn[r] = t;
        if (r15 == DCOL && r < NPG) dn[r] = t;
      }
  }
  wsync();

  // ---- P3: per-dst softmax -> dense bf16 alpha (accumulated; 1/den -> dn) ----
  if (lane < NPG) {
    int rs = csr_ptr[lane], re = csr_ptr[lane + 1];
    float dv = dn[lane];
    float m = -3.4e38f;
    for (int k = rs; k < re; ++k) {
      float e = sn[csr_src[k]] + dv;
      e = (e >= 0.f) ? e : 0.2f * e;
      m = fmaxf(m, e);
    }
    float den = 0.f;
    for (int k = rs; k < re; ++k) {
      int s = csr_src[k];
      float e = sn[s] + dv;
      e = (e >= 0.f) ? e : 0.2f * e;
      float w = __expf(e - m);
      int idx = lane * 64 + ((((s >> 3) ^ (lane & 7)) << 3)) + (s & 7);
      float cur = b2f(alf16[idx]);             // duplicate edges accumulate
      unsigned short nb = f2b(cur + w);
      alf16[idx] = nb;
      den += b2f(nb) - cur;                    // den == sum of stored values
    }
    dn[lane] = 1.f / (den + 1e-16f);
  }
  wsync();

  // ---- P4: Out = alpha @ H via MFMA, per Ht half ----
  float invr[3][4];
#pragma unroll
  for (int mt = 0; mt < 3; ++mt)
#pragma unroll
    for (int v = 0; v < 4; ++v) invr[mt][v] = dn[16 * mt + g * 4 + v];

  float pool_[NT_STORE];
#pragma unroll
  for (int s = 0; s < NT_STORE; ++s) pool_[s] = 0.f;

#pragma unroll
  for (int h = 0; h < HALVES; ++h) {
    if constexpr (Fi > 1) {
      // recompute P1 feature tiles for this half (A-loads are L1-hot)
      f32x4 c1[3][NTH];
#pragma unroll
      for (int mt = 0; mt < 3; ++mt)
#pragma unroll
        for (int tl = 0; tl < NTH; ++tl) c1[mt][tl] = z;
#pragma unroll
      for (int kt = 0; kt < KT1; ++kt) {
        bf16x8 aF[3];
#pragma unroll
        for (int mt = 0; mt < 3; ++mt)
          aF[mt] = *(const bf16x8*)&f_row[in_off + (16 * mt + r15) * Fi + kt * 32 + g * 8];
#pragma unroll
        for (int tl = 0; tl < NTH; ++tl) {
          int nt = h * NTH + tl;
          bf16x8 bW = *(const bf16x8*)&Wb[(16 * nt + r15) * KPAD + kt * 32 + g * 8];
#pragma unroll
          for (int mt = 0; mt < 3; ++mt)
            c1[mt][tl] = __builtin_amdgcn_mfma_f32_16x16x32_bf16(aF[mt], bW, c1[mt][tl], 0, 0, 0);
        }
      }
      // write Ht (transposed, swizzled): Ht[feat][src] = h[src][feat]
#pragma unroll
      for (int tl = 0; tl < NTH; ++tl) {
        int p = r15 + 16 * tl;
#pragma unroll
        for (int mt = 0; mt < 3; ++mt) {
          uint2 w;
          w.x = pk2(c1[mt][tl][0], c1[mt][tl][1]);
          w.y = pk2(c1[mt][tl][2], c1[mt][tl][3]);
          int idx = p * 64 + (((2 * mt + (g >> 1)) ^ (p & 7)) << 3) + (g & 1) * 4;
          *(uint2*)&Htb[idx] = w;
        }
      }
    }
    wsync();
    // alpha @ Ht
    f32x4 c2[3][NTH];
#pragma unroll
    for (int mt = 0; mt < 3; ++mt)
#pragma unroll
      for (int tl = 0; tl < NTH; ++tl) c2[mt][tl] = z;
#pragma unroll
    for (int kt = 0; kt < 2; ++kt) {
      bf16x8 aA[3];
#pragma unroll
      for (int mt = 0; mt < 3; ++mt) {
        int row = 16 * mt + r15;
        aA[mt] = *(const bf16x8*)&alf16[row * 64 + ((((4 * kt + g) ^ (row & 7))) << 3)];
      }
#pragma unroll
      for (int tl = 0; tl < NTH; ++tl) {
        int p = r15 + 16 * tl;
        bf16x8 bH = *(const bf16x8*)&Htb[p * 64 + ((((4 * kt + g) ^ (p & 7))) << 3)];
#pragma unroll
        for (int mt = 0; mt < 3; ++mt)
          c2[mt][tl] = __builtin_amdgcn_mfma_f32_16x16x32_bf16(aA[mt], bH, c2[mt][tl], 0, 0, 0);
      }
    }
    // epilogue: 1/den, bias, relu, residual stores, pool
#pragma unroll
    for (int tl = 0; tl < NTH; ++tl) {
      int c = r15 + 16 * (h * NTH + tl);
      float bv = (c < Fo) ? bias[c] : 0.f;
#pragma unroll
      for (int mt = 0; mt < 3; ++mt)
#pragma unroll
        for (int v = 0; v < 4; ++v) {
          int r = 16 * mt + g * 4 + v;
          float val = fmaxf(c2[mt][tl][v] * invr[mt][v] + bv, 0.f);
          if (r < NPG && c < Fo) {
            f_row[res_off + r * Fo + c] = f2b(val);
            pool_[h * NTH + tl] = fmaxf(pool_[h * NTH + tl], val);
          }
        }
    }
    wsync();                                   // before next half overwrites Ht
  }

  // ---- P5: per-graph max pool (cross-lane over row groups) ----
#pragma unroll
  for (int s = 0; s < NT_STORE; ++s) {
    float pv = pool_[s];
    pv = fmaxf(pv, __shfl_xor(pv, 16));
    pv = fmaxf(pv, __shfl_xor(pv, 32));
    int c = r15 + 16 * s;
    if (g == 0 && c < Fo) f_row[out_off + c] = f2b(pv);
  }
}

// =========================== fused GAT kernel ===========================
__global__ __launch_bounds__(64, 4) void gat_fused(
    const float* __restrict__ x, const int* __restrict__ ei,
    const float* __restrict__ W1, const float* __restrict__ as1, const float* __restrict__ ad1,
    const float* __restrict__ b1, const float* __restrict__ b2,
    const float* __restrict__ b3, const float* __restrict__ b4,
    const unsigned short* __restrict__ Wb,
    unsigned short* __restrict__ f) {
  const int b = blockIdx.x;
  const int lane = threadIdx.x;                    // one wave per graph
  const int base = b * NPG;
  const int* srcg = ei + (size_t)b * EPG;
  const int* dstg = ei + E0 + (size_t)b * EPG;
  unsigned short* f_row = f + (size_t)b * KP;
  int* cnt = (int*)sn;                             // alias: sn unused until layers
  const uint4 z4 = {0u, 0u, 0u, 0u};

  // zero Ht once (k in [39,64) stays zero forever; rows 8-15 zero for layer1)
#pragma unroll
  for (int i = 0; i < 4; ++i) *(uint4*)&Htb[lane * 8 + i * 512] = z4;

  // x load, res0, out0, zero columns (k=39 inserted zero col; 4561.. pad)
  float xv = 0.f;
  if (lane < NPG) {
    xv = x[(size_t)base + lane];
    f_row[lane] = f2b(xv);
  }
  if (lane == 0) f_row[39] = 0;
  if (lane < KP - 4561) f_row[4561 + lane] = 0;
  float mx = (lane < NPG) ? xv : -3.4e38f;
#pragma unroll
  for (int st = 1; st < 64; st <<= 1) { float t = __shfl_xor(mx, st); mx = fmaxf(mx, t); }
  if (lane == 0) f_row[4447] = f2b(mx);            // out0 = max over raw x
  if (lane < NPG) cnt[lane] = 1;                   // self loop pre-count
  wsync();

  // degree count (edges stashed in registers for the scatter pass)
  int es[5], ed[5];
#pragma unroll
  for (int it = 0; it < 5; ++it) {
    int e = lane + 64 * it;
    if (e < EPG) {
      int s = srcg[e] - base, d = dstg[e] - base;
      s = min(max(s, 0), NPG - 1);
      d = min(max(d, 0), NPG - 1);
      es[it] = s; ed[it] = d;
      atomicAdd(&cnt[d], 1);
    } else { es[it] = -1; ed[it] = 0; }
  }
  wsync();

  // exclusive prefix sum via wave scan (uniform control flow)
  int c = (lane < NPG) ? cnt[lane] : 0;
  int v = c;
#pragma unroll
  for (int off = 1; off < 64; off <<= 1) { int t = __shfl_up(v, off); if (lane >= off) v += t; }
  int excl = v - c;
  if (lane < NPG) csr_ptr[lane] = (unsigned short)excl;
  if (lane == NPG - 1) csr_ptr[NPG] = (unsigned short)EDG;
  wsync();
  if (lane < NPG) cnt[lane] = excl;                // running positions
  wsync();

  // scatter: self loops + edges
  if (lane < NPG) { int p = atomicAdd(&cnt[lane], 1); csr_src[p] = (unsigned char)lane; }
#pragma unroll
  for (int it = 0; it < 5; ++it) {
    if (es[it] >= 0) {
      int p = atomicAdd(&cnt[ed[it]], 1);
      p = min(p, EDG - 1);
      csr_src[p] = (unsigned char)es[it];
    }
  }
  wsync();

  const unsigned short* Wb2 = Wb;                  // [80][32]
  const unsigned short* Wb3 = Wb + 2560;           // [48][64]
  const unsigned short* Wb4 = Wb + 5632;           // [16][32]

  //      Fi  Fo KPAD KT1 NT HALV DT SCOL DCOL
  layerM< 1,  8,  0,  0,  1,  1,  0,  0,  0>(xv, nullptr, W1, as1, ad1, b1, f_row, 0,    40,   4448, lane);
  layerM< 8, 64, 32,  1,  4,  2,  4,  0,  1>(0.f, Wb2, nullptr, nullptr, nullptr, b2, f_row, 40,   352,  4456, lane);
  layerM<64, 32, 64,  2,  2,  1,  2,  0,  1>(0.f, Wb3, nullptr, nullptr, nullptr, b3, f_row, 352,  2848, 4520, lane);
  layerM<32,  9, 32,  1,  1,  1,  0, 10, 11>(0.f, Wb4, nullptr, nullptr, nullptr, b4, f_row, 2848, 4096, 4552, lane);
}

// ============ prep: W fragments (B^T layout) + attn-dot columns ============
// Wb2 [80][32]: rows 0-63 = W2^T (k<8, else 0); 64/65 = hi(W2@as2 / @ad2);
//               68/69 = lo residuals; rest 0.
// Wb3 [48][64]: rows 0-31 = W3^T; 32/33 hi; 36/37 lo; rest 0.
// Wb4 [16][32]: rows 0-8 = W4^T; 10/11 hi; 14/15 lo; rest 0.
__global__ __launch_bounds__(256) void prep_wb(
    const float* __restrict__ W2, const float* __restrict__ as2, const float* __restrict__ ad2,
    const float* __restrict__ W3, const float* __restrict__ as3, const float* __restrict__ ad3,
    const float* __restrict__ W4, const float* __restrict__ as4, const float* __restrict__ ad4,
    unsigned short* __restrict__ Wb) {
  const int tid = threadIdx.x;
  for (int i = tid; i < 80 * 32; i += 256) {
    int o = i >> 5, k = i & 31; float v = 0.f;
    if (k < 8) {
      if (o < 64) v = W2[k * 64 + o];
      else if (o == 64 || o == 68) { float s = 0; for (int j = 0; j < 64; ++j) s += W2[k * 64 + j] * as2[j];
        float hi = b2f(f2b(s)); v = (o == 64) ? hi : (s - hi); }
      else if (o == 65 || o == 69) { float s = 0; for (int j = 0; j < 64; ++j) s += W2[k * 64 + j] * ad2[j];
        float hi = b2f(f2b(s)); v = (o == 65) ? hi : (s - hi); }
    }
    Wb[i] = f2b(v);
  }
  for (int i = tid; i < 48 * 64; i += 256) {
    int o = i >> 6, k = i & 63; float v = 0.f;
    if (o < 32) v = W3[k * 32 + o];
    else if (o == 32 || o == 36) { float s = 0; for (int j = 0; j < 32; ++j) s += W3[k * 32 + j] * as3[j];
      float hi = b2f(f2b(s)); v = (o == 32) ? hi : (s - hi); }
    else if (o == 33 || o == 37) { float s = 0; for (int j = 0; j < 32; ++j) s += W3[k * 32 + j] * ad3[j];
      float hi = b2f(f2b(s)); v = (o == 33) ? hi : (s - hi); }
    Wb[2560 + i] = f2b(v);
  }
  for (int i = tid; i < 16 * 32; i += 256) {
    int o = i >> 5, k = i & 31; float v = 0.f;
    if (o < 9) v = W4[k * 9 + o];
    else if (o == 10 || o == 14) { float s = 0; for (int j = 0; j < 9; ++j) s += W4[k * 9 + j] * as4[j];
      float hi = b2f(f2b(s)); v = (o == 10) ? hi : (s - hi); }
    else if (o == 11 || o == 15) { float s = 0; for (int j = 0; j < 9; ++j) s += W4[k * 9 + j] * ad4[j];
      float hi = b2f(f2b(s)); v = (o == 11) ? hi : (s - hi); }
    Wb[5632 + i] = f2b(v);
  }
}

// ================= weight transpose + bf16 cast (per launch) =================
// PERM: apply the f-column permutation (insert zero col at k=39, shift +1)
template<bool PERM>
__global__ __launch_bounds__(256) void tcast(const float* __restrict__ in,
                                             unsigned short* __restrict__ out,
                                             int K, int NN, int Kpad) {
  __shared__ float tile[64 * 65];
  const int k0 = blockIdx.x * 64, n0 = blockIdx.y * 64;
  const int tid = threadIdx.x;
#pragma unroll
  for (int i = 0; i < 16; ++i) {
    int idx = i * 256 + tid;
    int r = idx >> 6, c = idx & 63;
    int k = k0 + r;
    int ko;
    if constexpr (PERM) {
      ko = (k < 39) ? k : ((k == 39 || k > FDIM) ? -1 : k - 1);
    } else {
      ko = (k < K) ? k : -1;
    }
    tile[r * 65 + c] = (ko >= 0) ? in[(size_t)ko * NN + n0 + c] : 0.f;
  }
  __syncthreads();
#pragma unroll
  for (int i = 0; i < 16; ++i) {
    int idx = i * 256 + tid;
    int r = idx >> 6, c = idx & 63;    // r: n-offset, c: k-offset
    out[(size_t)(n0 + r) * Kpad + k0 + c] = f2b(tile[c * 65 + r]);
  }
}

// =========================== bf16 MFMA GEMM ===========================
template<bool OUT_BF16>
__global__ __launch_bounds__(256) void mfma_gemm(const unsigned short* __restrict__ A,
    const unsigned short* __restrict__ Bt, unsigned short* __restrict__ Cb,
    float* __restrict__ Cf, const float* __restrict__ bias, int K, int N) {
  __shared__ alignas(16) unsigned short As[128 * 32];
  __shared__ alignas(16) unsigned short Bs[128 * 32];
  const int tid = threadIdx.x;
  const int lane = tid & 63;
  const int wave = tid >> 6;
  const int wy = wave >> 1, wx = wave & 1;
  const int m0 = blockIdx.y * 128, n0 = blockIdx.x * 128;

  f32x4 acc[4][4];
  const f32x4 z = {0.f, 0.f, 0.f, 0.f};
#pragma unroll
  for (int i = 0; i < 4; ++i)
#pragma unroll
    for (int j = 0; j < 4; ++j) acc[i][j] = z;

  const int lr = lane >> 2;
  const int lc = (lane & 3) * 8;
  const int q8 = (lane >> 4) * 8;
  const int rm = lane & 15;

  for (int k0 = 0; k0 < K; k0 += 32) {
    __syncthreads();
#pragma unroll
    for (int t = 0; t < 2; ++t) {
      int r0 = wave * 32 + t * 16;
      const unsigned short* ga = A  + (size_t)(m0 + r0 + lr) * K + k0 + lc;
      const unsigned short* gb = Bt + (size_t)(n0 + r0 + lr) * K + k0 + lc;
      __builtin_amdgcn_global_load_lds(
          (const __attribute__((address_space(1))) unsigned int*)(const void*)ga,
          (__attribute__((address_space(3))) unsigned int*)(void*)&As[r0 * 32], 16, 0, 0);
      __builtin_amdgcn_global_load_lds(
          (const __attribute__((address_space(1))) unsigned int*)(const void*)gb,
          (__attribute__((address_space(3))) unsigned int*)(void*)&Bs[r0 * 32], 16, 0, 0);
    }
    __syncthreads();
    bf16x8 af[4], bfr[4];
#pragma unroll
    for (int i = 0; i < 4; ++i) {
      af[i]  = *(const bf16x8*)&As[(wy * 64 + i * 16 + rm) * 32 + q8];
      bfr[i] = *(const bf16x8*)&Bs[(wx * 64 + i * 16 + rm) * 32 + q8];
    }
#pragma unroll
    for (int i = 0; i < 4; ++i)
#pragma unroll
      for (int j = 0; j < 4; ++j)
        acc[i][j] = __builtin_amdgcn_mfma_f32_16x16x32_bf16(af[i], bfr[j], acc[i][j], 0, 0, 0);
  }
  const int q4 = (lane >> 4) * 4;
#pragma unroll
  for (int i = 0; i < 4; ++i) {
#pragma unroll
    for (int j = 0; j < 4; ++j) {
      int row = m0 + wy * 64 + i * 16 + q4;
      int col = n0 + wx * 64 + j * 16 + rm;
      float bv = bias[col];
#pragma unroll
      for (int v = 0; v < 4; ++v) {
        float val = fmaxf(acc[i][j][v] + bv, 0.f);
        if constexpr (OUT_BF16) Cb[(size_t)(row + v) * N + col] = f2b(val);
        else                    Cf[(size_t)(row + v) * N + col] = val;
      }
    }
  }
}

// =========================== final 128->9 layer ===========================
__global__ __launch_bounds__(256) void mlp3(const float* __restrict__ g2,
                                            const float* __restrict__ w3,
                                            const float* __restrict__ b3,
                                            float* __restrict__ out) {
  __shared__ float gs[64 * 130];
  __shared__ float ws3[128 * 9];
  const int r0 = blockIdx.x * 64;
  const int tid = threadIdx.x;
  for (int i = tid; i < 64 * 128; i += 256)
    gs[(i >> 7) * 130 + (i & 127)] = g2[(size_t)r0 * 128 + i];
  for (int i = tid; i < 128 * 9; i += 256) ws3[i] = w3[i];
  __syncthreads();
  for (int idx = tid; idx < 64 * 9; idx += 256) {
    int r = idx / 9, c = idx - r * 9;
    float acc = b3[c];
#pragma unroll 8
    for (int k = 0; k < 128; ++k) acc += gs[r * 130 + k] * ws3[k * 9 + c];
    out[(size_t)(r0 + r) * 9 + c] = acc;
  }
}

// =========================== launch ===========================
extern "C" void kernel_launch(void* const* d_in, const int* in_sizes, int n_in,
                              void* d_out, int out_size, void* d_ws, size_t ws_size,
                              hipStream_t stream) {
  const float* x   = (const float*)d_in[0];
  const int*   ei  = (const int*)d_in[1];
  const float* W1  = (const float*)d_in[3];
  const float* as1 = (const float*)d_in[4];
  const float* ad1 = (const float*)d_in[5];
  const float* b1  = (const float*)d_in[6];
  const float* W2  = (const float*)d_in[7];
  const float* as2 = (const float*)d_in[8];
  const float* ad2 = (const float*)d_in[9];
  const float* b2  = (const float*)d_in[10];
  const float* W3  = (const float*)d_in[11];
  const float* as3 = (const float*)d_in[12];
  const float* ad3 = (const float*)d_in[13];
  const float* b3  = (const float*)d_in[14];
  const float* W4  = (const float*)d_in[15];
  const float* as4 = (const float*)d_in[16];
  const float* ad4 = (const float*)d_in[17];
  const float* b4  = (const float*)d_in[18];
  const float* lw1 = (const float*)d_in[19];
  const float* lb1 = (const float*)d_in[20];
  const float* lw2 = (const float*)d_in[21];
  const float* lb2 = (const float*)d_in[22];
  const float* lw3 = (const float*)d_in[23];
  const float* lb3 = (const float*)d_in[24];
  float* out = (float*)d_out;

  // workspace carve-up (bf16 stored as u16)
  unsigned short* f   = (unsigned short*)d_ws;            // [8192][4608] bf16
  unsigned short* w1t = f   + (size_t)NGRAPH * KP;        // [1024][4608] bf16
  unsigned short* w2t = w1t + (size_t)1024 * KP;          // [128][1024]  bf16
  unsigned short* g1  = w2t + (size_t)128 * 1024;         // [8192][1024] bf16
  float*          g2  = (float*)(g1 + (size_t)NGRAPH * 1024); // [8192][128] f32
  // W fragments live at the head of g1's space: consumed by gat_fused BEFORE
  // mfma_gemm1 writes g1 (stream-ordered, so safe). 6144 u16.
  unsigned short* Wb  = g1;

  prep_wb<<<1, 256, 0, stream>>>(W2, as2, ad2, W3, as3, ad3, W4, as4, ad4, Wb);
  tcast<true ><<<dim3(KP / 64, 1024 / 64), 256, 0, stream>>>(lw1, w1t, FDIM, 1024, KP);
  tcast<false><<<dim3(1024 / 64, 128 / 64), 256, 0, stream>>>(lw2, w2t, 1024, 128, 1024);

  gat_fused<<<NGRAPH, 64, 0, stream>>>(x, ei, W1, as1, ad1,
      b1, b2, b3, b4, Wb, f);

  mfma_gemm<true ><<<dim3(1024 / 128, NGRAPH / 128), 256, 0, stream>>>(
      f, w1t, g1, nullptr, lb1, KP, 1024);
  mfma_gemm<false><<<dim3(128 / 128, NGRAPH / 128), 256, 0, stream>>>(
      g1, w2t, nullptr, g2, lb2, 1024, 128);

  mlp3<<<NGRAPH / 64, 256, 0, stream>>>(g2, lw3, lb3, out);
}

// Round 9
// 225.904 us; speedup vs baseline: 1.6286x; 1.1659x over previous
//
#include <hip/hip_runtime.h>

// Problem constants
#define NPG   39
#define NGRAPH 8192
#define EPG   312           // input edges per graph
#define EDG   351           // + 39 self loops
#define E0    2555904       // total input edges (8192*312)
#define FDIM  4560
#define KP    4608          // padded K for bf16 GEMM (multiple of 128)

typedef __bf16 bf16x8 __attribute__((ext_vector_type(8)));
typedef float  f32x4  __attribute__((ext_vector_type(4)));

__device__ __forceinline__ unsigned short f2b(float f) {
  unsigned int u = __float_as_uint(f);
  u += 0x7fffu + ((u >> 16) & 1u);            // RNE to bf16
  return (unsigned short)(u >> 16);
}
__device__ __forceinline__ unsigned int pk2(float lo, float hi) {
  return (unsigned int)f2b(lo) | ((unsigned int)f2b(hi) << 16);
}
__device__ __forceinline__ float b2f(unsigned short u) {
  return __uint_as_float((unsigned int)u << 16);
}
// wave-level "barrier": single wave per workgroup -> LDS drain + compiler fence
__device__ __forceinline__ void wsync() {
  asm volatile("s_waitcnt lgkmcnt(0)" ::: "memory");
}
// drain global stores (f_row RAW across layers, same CU)
__device__ __forceinline__ void gsync() {
  asm volatile("s_waitcnt vmcnt(0) lgkmcnt(0)" ::: "memory");
}

// =================== per-graph LDS (one wave per graph) ===================
__shared__ alignas(16) unsigned short Htb[32 * 64];    // 4096 B
__shared__ alignas(16) unsigned short alf16[40 * 64];  // 5120 B
__shared__ float sn[40];                               // src attn scalars (alias: cnt)
__shared__ float dn[48];                               // d-dot, then 1/den (pad 48)
__shared__ unsigned char csr_src[EDG + 1];
__shared__ unsigned short csr_ptr[NPG + 1];

// ======================= fused GAT layer (per wave) =======================
template<int Fi, int Fo, int KPAD, int KT1, int NT_STORE, int HALVES,
         int DT, int SCOL, int DCOL>
__device__ __forceinline__ void layerM(float x0,
                                       const unsigned short* __restrict__ Wb,
                                       const float* __restrict__ W1,
                                       const float* __restrict__ as1,
                                       const float* __restrict__ ad1,
                                       const float* __restrict__ bias,
                                       unsigned short* __restrict__ f_row,
                                       int in_off, int res_off, int out_off,
                                       int lane) {
  constexpr int NTH = NT_STORE / HALVES;
  const int r15 = lane & 15, g = lane >> 4;
  const f32x4 z = {0.f, 0.f, 0.f, 0.f};
  const uint4 z4 = {0u, 0u, 0u, 0u};

  // ---- zero alpha (stale entries from previous layer; also k-padding) ----
#pragma unroll
  for (int i = 0; i < 5; ++i) *(uint4*)&alf16[lane * 8 + i * 512] = z4;

  // ---- P1-dots: attention scalars via 2 extra GEMM columns ----
  if constexpr (Fi == 1) {
    float was = 0.f, wad = 0.f;
#pragma unroll
    for (int o = 0; o < 8; ++o) { float w = W1[o]; was += w * as1[o]; wad += w * ad1[o]; }
    if (lane < NPG) {
      sn[lane] = x0 * was; dn[lane] = x0 * wad;
#pragma unroll
      for (int o = 0; o < 8; ++o) {
        int idx = o * 64 + ((((lane >> 3) ^ (o & 7)) << 3)) + (lane & 7);
        Htb[idx] = f2b(x0 * W1[o]);
      }
    }
  } else {
    gsync();                                   // prior layer's f stores
    f32x4 cd[3];
#pragma unroll
    for (int mt = 0; mt < 3; ++mt) cd[mt] = z;
#pragma unroll
    for (int kt = 0; kt < KT1; ++kt) {
      bf16x8 aF[3];
#pragma unroll
      for (int mt = 0; mt < 3; ++mt)
        aF[mt] = *(const bf16x8*)&f_row[in_off + (16 * mt + r15) * Fi + kt * 32 + g * 8];
      bf16x8 bD = *(const bf16x8*)&Wb[(16 * DT + r15) * KPAD + kt * 32 + g * 8];
#pragma unroll
      for (int mt = 0; mt < 3; ++mt)
        cd[mt] = __builtin_amdgcn_mfma_f32_16x16x32_bf16(aF[mt], bD, cd[mt], 0, 0, 0);
    }
#pragma unroll
    for (int mt = 0; mt < 3; ++mt)
#pragma unroll
      for (int v = 0; v < 4; ++v) {
        float t = cd[mt][v] + __shfl_xor(cd[mt][v], 4);   // hi + lo column
        int r = 16 * mt + g * 4 + v;
        if (r15 == SCOL && r < NPG) sn[r] = t;
        if (r15 == DCOL && r < NPG) dn[r] = t;
      }
  }
  wsync();

  // ---- P3: per-dst softmax -> dense bf16 alpha (accumulated; 1/den -> dn) ----
  if (lane < NPG) {
    int rs = csr_ptr[lane], re = csr_ptr[lane + 1];
    float dv = dn[lane];
    float m = -3.4e38f;
    for (int k = rs; k < re; ++k) {
      float e = sn[csr_src[k]] + dv;
      e = (e >= 0.f) ? e : 0.2f * e;
      m = fmaxf(m, e);
    }
    float den = 0.f;
    for (int k = rs; k < re; ++k) {
      int s = csr_src[k];
      float e = sn[s] + dv;
      e = (e >= 0.f) ? e : 0.2f * e;
      float w = __expf(e - m);
      int idx = lane * 64 + ((((s >> 3) ^ (lane & 7)) << 3)) + (s & 7);
      float cur = b2f(alf16[idx]);             // duplicate edges accumulate
      unsigned short nb = f2b(cur + w);
      alf16[idx] = nb;
      den += b2f(nb) - cur;                    // den == sum of stored values
    }
    dn[lane] = 1.f / (den + 1e-16f);
  }
  wsync();

  // ---- P4: Out = alpha @ H via MFMA, per Ht half ----
  float invr[3][4];
#pragma unroll
  for (int mt = 0; mt < 3; ++mt)
#pragma unroll
    for (int v = 0; v < 4; ++v) invr[mt][v] = dn[16 * mt + g * 4 + v];

  float pool_[NT_STORE];
#pragma unroll
  for (int s = 0; s < NT_STORE; ++s) pool_[s] = 0.f;

#pragma unroll
  for (int h = 0; h < HALVES; ++h) {
    if constexpr (Fi > 1) {
      f32x4 c1[3][NTH];
#pragma unroll
      for (int mt = 0; mt < 3; ++mt)
#pragma unroll
        for (int tl = 0; tl < NTH; ++tl) c1[mt][tl] = z;
#pragma unroll
      for (int kt = 0; kt < KT1; ++kt) {
        bf16x8 aF[3];
#pragma unroll
        for (int mt = 0; mt < 3; ++mt)
          aF[mt] = *(const bf16x8*)&f_row[in_off + (16 * mt + r15) * Fi + kt * 32 + g * 8];
#pragma unroll
        for (int tl = 0; tl < NTH; ++tl) {
          int nt = h * NTH + tl;
          bf16x8 bW = *(const bf16x8*)&Wb[(16 * nt + r15) * KPAD + kt * 32 + g * 8];
#pragma unroll
          for (int mt = 0; mt < 3; ++mt)
            c1[mt][tl] = __builtin_amdgcn_mfma_f32_16x16x32_bf16(aF[mt], bW, c1[mt][tl], 0, 0, 0);
        }
      }
#pragma unroll
      for (int tl = 0; tl < NTH; ++tl) {
        int p = r15 + 16 * tl;
#pragma unroll
        for (int mt = 0; mt < 3; ++mt) {
          uint2 w;
          w.x = pk2(c1[mt][tl][0], c1[mt][tl][1]);
          w.y = pk2(c1[mt][tl][2], c1[mt][tl][3]);
          int idx = p * 64 + (((2 * mt + (g >> 1)) ^ (p & 7)) << 3) + (g & 1) * 4;
          *(uint2*)&Htb[idx] = w;
        }
      }
    }
    wsync();
    // alpha @ Ht
    f32x4 c2[3][NTH];
#pragma unroll
    for (int mt = 0; mt < 3; ++mt)
#pragma unroll
      for (int tl = 0; tl < NTH; ++tl) c2[mt][tl] = z;
#pragma unroll
    for (int kt = 0; kt < 2; ++kt) {
      bf16x8 aA[3];
#pragma unroll
      for (int mt = 0; mt < 3; ++mt) {
        int row = 16 * mt + r15;
        aA[mt] = *(const bf16x8*)&alf16[row * 64 + ((((4 * kt + g) ^ (row & 7))) << 3)];
      }
#pragma unroll
      for (int tl = 0; tl < NTH; ++tl) {
        int p = r15 + 16 * tl;
        bf16x8 bH = *(const bf16x8*)&Htb[p * 64 + ((((4 * kt + g) ^ (p & 7))) << 3)];
#pragma unroll
        for (int mt = 0; mt < 3; ++mt)
          c2[mt][tl] = __builtin_amdgcn_mfma_f32_16x16x32_bf16(aA[mt], bH, c2[mt][tl], 0, 0, 0);
      }
    }
#pragma unroll
    for (int tl = 0; tl < NTH; ++tl) {
      int c = r15 + 16 * (h * NTH + tl);
      float bv = (c < Fo) ? bias[c] : 0.f;
#pragma unroll
      for (int mt = 0; mt < 3; ++mt)
#pragma unroll
        for (int v = 0; v < 4; ++v) {
          int r = 16 * mt + g * 4 + v;
          float val = fmaxf(c2[mt][tl][v] * invr[mt][v] + bv, 0.f);
          if (r < NPG && c < Fo) {
            f_row[res_off + r * Fo + c] = f2b(val);
            pool_[h * NTH + tl] = fmaxf(pool_[h * NTH + tl], val);
          }
        }
    }
    wsync();                                   // before next half overwrites Ht
  }

  // ---- P5: per-graph max pool (cross-lane over row groups) ----
#pragma unroll
  for (int s = 0; s < NT_STORE; ++s) {
    float pv = pool_[s];
    pv = fmaxf(pv, __shfl_xor(pv, 16));
    pv = fmaxf(pv, __shfl_xor(pv, 32));
    int c = r15 + 16 * s;
    if (g == 0 && c < Fo) f_row[out_off + c] = f2b(pv);
  }
}

// =========================== fused GAT kernel ===========================
__global__ __launch_bounds__(64, 4) void gat_fused(
    const float* __restrict__ x, const int* __restrict__ ei,
    const float* __restrict__ W1, const float* __restrict__ as1, const float* __restrict__ ad1,
    const float* __restrict__ b1, const float* __restrict__ b2,
    const float* __restrict__ b3, const float* __restrict__ b4,
    const unsigned short* __restrict__ Wb,
    unsigned short* __restrict__ f) {
  const int b = blockIdx.x;
  const int lane = threadIdx.x;                    // one wave per graph
  const int base = b * NPG;
  const int* srcg = ei + (size_t)b * EPG;
  const int* dstg = ei + E0 + (size_t)b * EPG;
  unsigned short* f_row = f + (size_t)b * KP;
  int* cnt = (int*)sn;                             // alias: sn unused until layers
  const uint4 z4 = {0u, 0u, 0u, 0u};

  // zero Ht once (k in [39,64) stays zero forever; rows 8-15 zero for layer1)
#pragma unroll
  for (int i = 0; i < 4; ++i) *(uint4*)&Htb[lane * 8 + i * 512] = z4;

  // x load, res0, out0, zero columns (k=39 inserted zero col; 4561.. pad)
  float xv = 0.f;
  if (lane < NPG) {
    xv = x[(size_t)base + lane];
    f_row[lane] = f2b(xv);
  }
  if (lane == 0) f_row[39] = 0;
  if (lane < KP - 4561) f_row[4561 + lane] = 0;
  float mx = (lane < NPG) ? xv : -3.4e38f;
#pragma unroll
  for (int st = 1; st < 64; st <<= 1) { float t = __shfl_xor(mx, st); mx = fmaxf(mx, t); }
  if (lane == 0) f_row[4447] = f2b(mx);            // out0 = max over raw x
  if (lane < NPG) cnt[lane] = 1;                   // self loop pre-count
  wsync();

  // degree count (edges stashed in registers for the scatter pass)
  int es[5], ed[5];
#pragma unroll
  for (int it = 0; it < 5; ++it) {
    int e = lane + 64 * it;
    if (e < EPG) {
      int s = srcg[e] - base, d = dstg[e] - base;
      s = min(max(s, 0), NPG - 1);
      d = min(max(d, 0), NPG - 1);
      es[it] = s; ed[it] = d;
      atomicAdd(&cnt[d], 1);
    } else { es[it] = -1; ed[it] = 0; }
  }
  wsync();

  // exclusive prefix sum via wave scan (uniform control flow)
  int c = (lane < NPG) ? cnt[lane] : 0;
  int v = c;
#pragma unroll
  for (int off = 1; off < 64; off <<= 1) { int t = __shfl_up(v, off); if (lane >= off) v += t; }
  int excl = v - c;
  if (lane < NPG) csr_ptr[lane] = (unsigned short)excl;
  if (lane == NPG - 1) csr_ptr[NPG] = (unsigned short)EDG;
  wsync();
  if (lane < NPG) cnt[lane] = excl;                // running positions
  wsync();

  // scatter: self loops + edges
  if (lane < NPG) { int p = atomicAdd(&cnt[lane], 1); csr_src[p] = (unsigned char)lane; }
#pragma unroll
  for (int it = 0; it < 5; ++it) {
    if (es[it] >= 0) {
      int p = atomicAdd(&cnt[ed[it]], 1);
      p = min(p, EDG - 1);
      csr_src[p] = (unsigned char)es[it];
    }
  }
  wsync();

  const unsigned short* Wb2 = Wb;                  // [80][32]
  const unsigned short* Wb3 = Wb + 2560;           // [48][64]
  const unsigned short* Wb4 = Wb + 5632;           // [16][32]

  //      Fi  Fo KPAD KT1 NT HALV DT SCOL DCOL
  layerM< 1,  8,  0,  0,  1,  1,  0,  0,  0>(xv, nullptr, W1, as1, ad1, b1, f_row, 0,    40,   4448, lane);
  layerM< 8, 64, 32,  1,  4,  2,  4,  0,  1>(0.f, Wb2, nullptr, nullptr, nullptr, b2, f_row, 40,   352,  4456, lane);
  layerM<64, 32, 64,  2,  2,  1,  2,  0,  1>(0.f, Wb3, nullptr, nullptr, nullptr, b3, f_row, 352,  2848, 4520, lane);
  layerM<32,  9, 32,  1,  1,  1,  0, 10, 11>(0.f, Wb4, nullptr, nullptr, nullptr, b4, f_row, 2848, 4096, 4552, lane);
}

// ============ prep: W fragments (B^T layout) + attn-dot columns ============
__global__ __launch_bounds__(256) void prep_wb(
    const float* __restrict__ W2, const float* __restrict__ as2, const float* __restrict__ ad2,
    const float* __restrict__ W3, const float* __restrict__ as3, const float* __restrict__ ad3,
    const float* __restrict__ W4, const float* __restrict__ as4, const float* __restrict__ ad4,
    unsigned short* __restrict__ Wb) {
  const int tid = threadIdx.x;
  for (int i = tid; i < 80 * 32; i += 256) {
    int o = i >> 5, k = i & 31; float v = 0.f;
    if (k < 8) {
      if (o < 64) v = W2[k * 64 + o];
      else if (o == 64 || o == 68) { float s = 0; for (int j = 0; j < 64; ++j) s += W2[k * 64 + j] * as2[j];
        float hi = b2f(f2b(s)); v = (o == 64) ? hi : (s - hi); }
      else if (o == 65 || o == 69) { float s = 0; for (int j = 0; j < 64; ++j) s += W2[k * 64 + j] * ad2[j];
        float hi = b2f(f2b(s)); v = (o == 65) ? hi : (s - hi); }
    }
    Wb[i] = f2b(v);
  }
  for (int i = tid; i < 48 * 64; i += 256) {
    int o = i >> 6, k = i & 63; float v = 0.f;
    if (o < 32) v = W3[k * 32 + o];
    else if (o == 32 || o == 36) { float s = 0; for (int j = 0; j < 32; ++j) s += W3[k * 32 + j] * as3[j];
      float hi = b2f(f2b(s)); v = (o == 32) ? hi : (s - hi); }
    else if (o == 33 || o == 37) { float s = 0; for (int j = 0; j < 32; ++j) s += W3[k * 32 + j] * ad3[j];
      float hi = b2f(f2b(s)); v = (o == 33) ? hi : (s - hi); }
    Wb[2560 + i] = f2b(v);
  }
  for (int i = tid; i < 16 * 32; i += 256) {
    int o = i >> 5, k = i & 31; float v = 0.f;
    if (o < 9) v = W4[k * 9 + o];
    else if (o == 10 || o == 14) { float s = 0; for (int j = 0; j < 9; ++j) s += W4[k * 9 + j] * as4[j];
      float hi = b2f(f2b(s)); v = (o == 10) ? hi : (s - hi); }
    else if (o == 11 || o == 15) { float s = 0; for (int j = 0; j < 9; ++j) s += W4[k * 9 + j] * ad4[j];
      float hi = b2f(f2b(s)); v = (o == 11) ? hi : (s - hi); }
    Wb[5632 + i] = f2b(v);
  }
}

// ================= weight transpose + bf16 cast (per launch) =================
template<bool PERM>
__global__ __launch_bounds__(256) void tcast(const float* __restrict__ in,
                                             unsigned short* __restrict__ out,
                                             int K, int NN, int Kpad) {
  __shared__ float tile[64 * 65];
  const int k0 = blockIdx.x * 64, n0 = blockIdx.y * 64;
  const int tid = threadIdx.x;
#pragma unroll
  for (int i = 0; i < 16; ++i) {
    int idx = i * 256 + tid;
    int r = idx >> 6, c = idx & 63;
    int k = k0 + r;
    int ko;
    if constexpr (PERM) {
      ko = (k < 39) ? k : ((k == 39 || k > FDIM) ? -1 : k - 1);
    } else {
      ko = (k < K) ? k : -1;
    }
    tile[r * 65 + c] = (ko >= 0) ? in[(size_t)ko * NN + n0 + c] : 0.f;
  }
  __syncthreads();
#pragma unroll
  for (int i = 0; i < 16; ++i) {
    int idx = i * 256 + tid;
    int r = idx >> 6, c = idx & 63;    // r: n-offset, c: k-offset
    out[(size_t)(n0 + r) * Kpad + k0 + c] = f2b(tile[c * 65 + r]);
  }
}

// =========================== bf16 MFMA GEMM (BK=64, swizzled, XCD-clustered) ===========================
// 1-D grid. Mapping: xcd = wg&7 owns m-rows [xcd*mpr, (xcd+1)*mpr); n varies
// fastest within an m-row so the A-tile is L2-resident per XCD and reused
// gridN times. LDS: XOR-swizzle 16B chunks within each 128B row (applied to
// the GLOBAL source so global_load_lds dest stays linear; reads un-swizzle).
template<bool OUT_BF16>
__global__ __launch_bounds__(256) void mfma_gemm(const unsigned short* __restrict__ A,
    const unsigned short* __restrict__ Bt, unsigned short* __restrict__ Cb,
    float* __restrict__ Cf, const float* __restrict__ bias, int K, int N, int gridN) {
  __shared__ alignas(16) unsigned short As[128 * 64];
  __shared__ alignas(16) unsigned short Bs[128 * 64];
  const int tid = threadIdx.x;
  const int lane = tid & 63;
  const int wave = tid >> 6;
  const int wy = wave >> 1, wx = wave & 1;

  const int wg = blockIdx.x;
  const int xcd = wg & 7, idx = wg >> 3;
  const int mpr = (int)(gridDim.x >> 3) / gridN;   // m-rows per XCD
  const int m_local = idx / gridN;
  const int n = idx - m_local * gridN;
  const int m0 = (xcd * mpr + m_local) * 128;
  const int n0 = n * 128;

  f32x4 acc[4][4];
  const f32x4 z = {0.f, 0.f, 0.f, 0.f};
#pragma unroll
  for (int i = 0; i < 4; ++i)
#pragma unroll
    for (int j = 0; j < 4; ++j) acc[i][j] = z;

  const int srow = lane >> 3;                  // row within 8-row store group
  const int sch  = (lane & 7) ^ srow;          // swizzled source 16B chunk
  const int q    = lane >> 4;                  // k sub-chunk 0..3
  const int rm   = lane & 15;

  for (int k0 = 0; k0 < K; k0 += 64) {
    __syncthreads();
#pragma unroll
    for (int t = 0; t < 4; ++t) {
      int r0 = wave * 32 + t * 8;
      const unsigned short* ga = A  + (size_t)(m0 + r0 + srow) * K + k0 + sch * 8;
      const unsigned short* gb = Bt + (size_t)(n0 + r0 + srow) * K + k0 + sch * 8;
      __builtin_amdgcn_global_load_lds(
          (const __attribute__((address_space(1))) unsigned int*)(const void*)ga,
          (__attribute__((address_space(3))) unsigned int*)(void*)&As[r0 * 64], 16, 0, 0);
      __builtin_amdgcn_global_load_lds(
          (const __attribute__((address_space(1))) unsigned int*)(const void*)gb,
          (__attribute__((address_space(3))) unsigned int*)(void*)&Bs[r0 * 64], 16, 0, 0);
    }
    __syncthreads();
#pragma unroll
    for (int kk = 0; kk < 2; ++kk) {
      bf16x8 af[4], bfr[4];
#pragma unroll
      for (int i = 0; i < 4; ++i) {
        int ra = wy * 64 + i * 16 + rm;
        int rb = wx * 64 + i * 16 + rm;
        af[i]  = *(const bf16x8*)&As[ra * 64 + (((kk * 4 + q) ^ (ra & 7)) << 3)];
        bfr[i] = *(const bf16x8*)&Bs[rb * 64 + (((kk * 4 + q) ^ (rb & 7)) << 3)];
      }
#pragma unroll
      for (int i = 0; i < 4; ++i)
#pragma unroll
        for (int j = 0; j < 4; ++j)
          acc[i][j] = __builtin_amdgcn_mfma_f32_16x16x32_bf16(af[i], bfr[j], acc[i][j], 0, 0, 0);
    }
  }
  const int q4 = (lane >> 4) * 4;
#pragma unroll
  for (int i = 0; i < 4; ++i) {
#pragma unroll
    for (int j = 0; j < 4; ++j) {
      int row = m0 + wy * 64 + i * 16 + q4;
      int col = n0 + wx * 64 + j * 16 + rm;
      float bv = bias[col];
#pragma unroll
      for (int v = 0; v < 4; ++v) {
        float val = fmaxf(acc[i][j][v] + bv, 0.f);
        if constexpr (OUT_BF16) Cb[(size_t)(row + v) * N + col] = f2b(val);
        else                    Cf[(size_t)(row + v) * N + col] = val;
      }
    }
  }
}

// =========================== final 128->9 layer ===========================
__global__ __launch_bounds__(256) void mlp3(const float* __restrict__ g2,
                                            const float* __restrict__ w3,
                                            const float* __restrict__ b3,
                                            float* __restrict__ out) {
  __shared__ float gs[64 * 130];
  __shared__ float ws3[128 * 9];
  const int r0 = blockIdx.x * 64;
  const int tid = threadIdx.x;
  for (int i = tid; i < 64 * 128; i += 256)
    gs[(i >> 7) * 130 + (i & 127)] = g2[(size_t)r0 * 128 + i];
  for (int i = tid; i < 128 * 9; i += 256) ws3[i] = w3[i];
  __syncthreads();
  for (int idx = tid; idx < 64 * 9; idx += 256) {
    int r = idx / 9, c = idx - r * 9;
    float acc = b3[c];
#pragma unroll 8
    for (int k = 0; k < 128; ++k) acc += gs[r * 130 + k] * ws3[k * 9 + c];
    out[(size_t)(r0 + r) * 9 + c] = acc;
  }
}

// =========================== launch ===========================
extern "C" void kernel_launch(void* const* d_in, const int* in_sizes, int n_in,
                              void* d_out, int out_size, void* d_ws, size_t ws_size,
                              hipStream_t stream) {
  const float* x   = (const float*)d_in[0];
  const int*   ei  = (const int*)d_in[1];
  const float* W1  = (const float*)d_in[3];
  const float* as1 = (const float*)d_in[4];
  const float* ad1 = (const float*)d_in[5];
  const float* b1  = (const float*)d_in[6];
  const float* W2  = (const float*)d_in[7];
  const float* as2 = (const float*)d_in[8];
  const float* ad2 = (const float*)d_in[9];
  const float* b2  = (const float*)d_in[10];
  const float* W3  = (const float*)d_in[11];
  const float* as3 = (const float*)d_in[12];
  const float* ad3 = (const float*)d_in[13];
  const float* b3  = (const float*)d_in[14];
  const float* W4  = (const float*)d_in[15];
  const float* as4 = (const float*)d_in[16];
  const float* ad4 = (const float*)d_in[17];
  const float* b4  = (const float*)d_in[18];
  const float* lw1 = (const float*)d_in[19];
  const float* lb1 = (const float*)d_in[20];
  const float* lw2 = (const float*)d_in[21];
  const float* lb2 = (const float*)d_in[22];
  const float* lw3 = (const float*)d_in[23];
  const float* lb3 = (const float*)d_in[24];
  float* out = (float*)d_out;

  // workspace carve-up (bf16 stored as u16)
  unsigned short* f   = (unsigned short*)d_ws;            // [8192][4608] bf16
  unsigned short* w1t = f   + (size_t)NGRAPH * KP;        // [1024][4608] bf16
  unsigned short* w2t = w1t + (size_t)1024 * KP;          // [128][1024]  bf16
  unsigned short* g1  = w2t + (size_t)128 * 1024;         // [8192][1024] bf16
  float*          g2  = (float*)(g1 + (size_t)NGRAPH * 1024); // [8192][128] f32
  unsigned short* Wb  = g1;   // GAT W fragments; consumed before g1 is written

  prep_wb<<<1, 256, 0, stream>>>(W2, as2, ad2, W3, as3, ad3, W4, as4, ad4, Wb);
  tcast<true ><<<dim3(KP / 64, 1024 / 64), 256, 0, stream>>>(lw1, w1t, FDIM, 1024, KP);
  tcast<false><<<dim3(1024 / 64, 128 / 64), 256, 0, stream>>>(lw2, w2t, 1024, 128, 1024);

  gat_fused<<<NGRAPH, 64, 0, stream>>>(x, ei, W1, as1, ad1,
      b1, b2, b3, b4, Wb, f);

  mfma_gemm<true ><<<512, 256, 0, stream>>>(
      f, w1t, g1, nullptr, lb1, KP, 1024, 8);
  mfma_gemm<false><<<64, 256, 0, stream>>>(
      g1, w2t, nullptr, g2, lb2, 1024, 128, 1);

  mlp3<<<NGRAPH / 64, 256, 0, stream>>>(g2, lw3, lb3, out);
}